// Round 1
// 2527.305 us; speedup vs baseline: 2.0636x; 2.0636x over previous
//
#include <hip/hip_runtime.h>
#include <cstddef>

#define DIM   1024
#define VOCAB 32000
#define BATCH 2
#define SEQ   2048
#define CTX   4
#define EPS_D 1e-6f
#define LN_EPS 1e-5f

typedef __bf16 bf16x8 __attribute__((ext_vector_type(8)));
typedef float  f32x4  __attribute__((ext_vector_type(4)));
typedef unsigned short ushortx8 __attribute__((ext_vector_type(8)));

// fp32 -> bf16 round-to-nearest-even
__device__ __forceinline__ unsigned short f2bf(float f) {
    unsigned u = __float_as_uint(f);
    u += 0x7fffu + ((u >> 16) & 1u);
    return (unsigned short)(u >> 16);
}
__device__ __forceinline__ float bf2f(unsigned short h) {
    return __uint_as_float((unsigned)h << 16);
}

// async global->LDS, 16B per lane (dest must be lane-linear; swizzle goes on
// the GLOBAL source side — guide rule #21)
#define GL16(gp, lp) __builtin_amdgcn_global_load_lds(                        \
    (const __attribute__((address_space(1))) void*)(gp),                      \
    (__attribute__((address_space(3))) void*)(lp), 16, 0, 0)

// ---------------------------------------------------------------------------
// K1: embedding gather + local context sum
// ---------------------------------------------------------------------------
__global__ __launch_bounds__(256)
void embed_ctx_kernel(const int* __restrict__ x,
                      const float* __restrict__ table,
                      float* __restrict__ emb) {
    int bs = blockIdx.x;
    int b = bs >> 11;
    int s = bs & (SEQ - 1);
    int d = threadIdx.x * 4;
    float4 acc = make_float4(0.f, 0.f, 0.f, 0.f);
    #pragma unroll
    for (int o = 0; o < CTX; ++o) {
        int ss = s - o;
        if (ss >= 0) {
            int row = x[b * SEQ + ss];
            const float4 v = *(const float4*)&table[(size_t)row * DIM + d];
            acc.x += v.x; acc.y += v.y; acc.z += v.z; acc.w += v.w;
        }
    }
    *(float4*)&emb[(size_t)bs * DIM + d] = acc;
}

// ---------------------------------------------------------------------------
// Generic fp32 GEMM (kept for q/k/v, num, out-proj, and logits fallback)
// ---------------------------------------------------------------------------
template<int ACT, bool HAS_BIAS, bool HAS_DIV>
__global__ __launch_bounds__(256)
void gemm_kernel(const float* __restrict__ A,
                 const float* __restrict__ B,
                 const float* __restrict__ bias,
                 const float* __restrict__ rowdiv,
                 float* __restrict__ C,
                 int M, int N, int K) {
    __shared__ float As[16][64];
    __shared__ float Bs[16][64];

    const int tid = threadIdx.x;
    const int tx = tid & 15;
    const int ty = tid >> 4;
    const int row0 = blockIdx.y * 64;
    const int col0 = blockIdx.x * 64;

    const int a_row = tid >> 2;
    const int a_col = (tid & 3) * 4;
    const int b_row = tid >> 4;
    const int b_col = (tid & 15) * 4;

    const float* Aptr = A + (size_t)(row0 + a_row) * K + a_col;
    const float* Bptr = B + (size_t)b_row * N + col0 + b_col;

    float acc[4][4];
    #pragma unroll
    for (int i = 0; i < 4; ++i)
        #pragma unroll
        for (int j = 0; j < 4; ++j) acc[i][j] = 0.f;

    for (int k0 = 0; k0 < K; k0 += 16) {
        float4 a4 = *(const float4*)(Aptr + k0);
        float4 b4 = *(const float4*)(Bptr + (size_t)k0 * N);
        As[a_col + 0][a_row] = a4.x;
        As[a_col + 1][a_row] = a4.y;
        As[a_col + 2][a_row] = a4.z;
        As[a_col + 3][a_row] = a4.w;
        *(float4*)&Bs[b_row][b_col] = b4;
        __syncthreads();
        #pragma unroll
        for (int kk = 0; kk < 16; ++kk) {
            float4 av = *(const float4*)&As[kk][ty * 4];
            float4 bv = *(const float4*)&Bs[kk][tx * 4];
            float am[4] = {av.x, av.y, av.z, av.w};
            float bm[4] = {bv.x, bv.y, bv.z, bv.w};
            #pragma unroll
            for (int i = 0; i < 4; ++i)
                #pragma unroll
                for (int j = 0; j < 4; ++j)
                    acc[i][j] = fmaf(am[i], bm[j], acc[i][j]);
        }
        __syncthreads();
    }

    #pragma unroll
    for (int i = 0; i < 4; ++i) {
        const int r = row0 + ty * 4 + i;
        float rdiv = 1.f;
        if (HAS_DIV) rdiv = 1.f / rowdiv[r];
        #pragma unroll
        for (int j = 0; j < 4; ++j) {
            const int c = col0 + tx * 4 + j;
            float v = acc[i][j] * rdiv;
            if (HAS_BIAS) v += bias[c];
            if (ACT == 1) v = (v > 0.f) ? (v + 1.f) : __expf(v);
            C[(size_t)r * N + c] = v;
        }
    }
}

// ---------------------------------------------------------------------------
// Causal scores (unchanged)
// ---------------------------------------------------------------------------
__global__ __launch_bounds__(256)
void scores_kernel(const float* __restrict__ q,
                   const float* __restrict__ k,
                   float* __restrict__ scores) {
    const int b = blockIdx.z;
    const int tid = threadIdx.x;
    const int tx = tid & 15;
    const int ty = tid >> 4;
    const int i0 = blockIdx.y * 64;
    const int j0 = blockIdx.x * 64;
    float* Sc = scores + (size_t)b * SEQ * SEQ;

    if (j0 > i0 + 63) {
        #pragma unroll
        for (int i = 0; i < 4; ++i)
            #pragma unroll
            for (int j = 0; j < 4; ++j)
                Sc[(size_t)(i0 + ty * 4 + i) * SEQ + j0 + tx * 4 + j] = 0.f;
        return;
    }

    const float* Q = q + (size_t)b * SEQ * DIM;
    const float* Kp = k + (size_t)b * SEQ * DIM;

    __shared__ float Qs[16][64];
    __shared__ float Ks[16][64];

    const int l_row = tid >> 2;
    const int l_col = (tid & 3) * 4;

    const float* Qptr = Q + (size_t)(i0 + l_row) * DIM + l_col;
    const float* Kptr = Kp + (size_t)(j0 + l_row) * DIM + l_col;

    float acc[4][4];
    #pragma unroll
    for (int i = 0; i < 4; ++i)
        #pragma unroll
        for (int j = 0; j < 4; ++j) acc[i][j] = 0.f;

    for (int d0 = 0; d0 < DIM; d0 += 16) {
        float4 a4 = *(const float4*)(Qptr + d0);
        float4 b4 = *(const float4*)(Kptr + d0);
        Qs[l_col + 0][l_row] = a4.x;
        Qs[l_col + 1][l_row] = a4.y;
        Qs[l_col + 2][l_row] = a4.z;
        Qs[l_col + 3][l_row] = a4.w;
        Ks[l_col + 0][l_row] = b4.x;
        Ks[l_col + 1][l_row] = b4.y;
        Ks[l_col + 2][l_row] = b4.z;
        Ks[l_col + 3][l_row] = b4.w;
        __syncthreads();
        #pragma unroll
        for (int kk = 0; kk < 16; ++kk) {
            float4 av = *(const float4*)&Qs[kk][ty * 4];
            float4 bv = *(const float4*)&Ks[kk][tx * 4];
            float am[4] = {av.x, av.y, av.z, av.w};
            float bm[4] = {bv.x, bv.y, bv.z, bv.w};
            #pragma unroll
            for (int i = 0; i < 4; ++i)
                #pragma unroll
                for (int j = 0; j < 4; ++j)
                    acc[i][j] = fmaf(am[i], bm[j], acc[i][j]);
        }
        __syncthreads();
    }

    #pragma unroll
    for (int i = 0; i < 4; ++i) {
        const int ii = i0 + ty * 4 + i;
        #pragma unroll
        for (int j = 0; j < 4; ++j) {
            const int jj = j0 + tx * 4 + j;
            Sc[(size_t)ii * SEQ + jj] = (jj <= ii) ? acc[i][j] : 0.f;
        }
    }
}

__device__ __forceinline__ float block_reduce_sum(float v, float* red) {
    #pragma unroll
    for (int off = 32; off > 0; off >>= 1) v += __shfl_down(v, off);
    const int lane = threadIdx.x & 63;
    const int wid = threadIdx.x >> 6;
    if (lane == 0) red[wid] = v;
    __syncthreads();
    float s = red[0] + red[1] + red[2] + red[3];
    return s;
}

__global__ __launch_bounds__(256)
void den_kernel(const float* __restrict__ scores, float* __restrict__ den) {
    const int row = blockIdx.x;
    const int b = row >> 11;
    const int i = row & (SEQ - 1);
    const float* r = scores + (size_t)b * SEQ * SEQ + (size_t)i * SEQ;
    float s = 0.f;
    for (int j = threadIdx.x * 4; j < SEQ; j += 256 * 4) {
        float4 v = *(const float4*)&r[j];
        s += v.x + v.y + v.z + v.w;
    }
    __shared__ float red[4];
    float tot = block_reduce_sum(s, red);
    if (threadIdx.x == 0) den[row] = tot + EPS_D;
}

// ---------------------------------------------------------------------------
// LayerNorm in-place + optional hi/lo bf16 split of the result (A operand
// of the logits GEMM).
// ---------------------------------------------------------------------------
__global__ __launch_bounds__(256)
void ln_split_kernel(float* __restrict__ io,
                     const float* __restrict__ gamma,
                     const float* __restrict__ beta,
                     ushort* __restrict__ ahi,
                     ushort* __restrict__ alo,
                     int do_split) {
    const size_t row = blockIdx.x;
    float* r = io + row * DIM;
    const int d = threadIdx.x * 4;
    float4 v = *(const float4*)&r[d];
    float s = v.x + v.y + v.z + v.w;
    float sq = v.x * v.x + v.y * v.y + v.z * v.z + v.w * v.w;
    __shared__ float r1[4];
    __shared__ float r2[4];
    float tot = block_reduce_sum(s, r1);
    __syncthreads();
    float totsq = block_reduce_sum(sq, r2);
    const float mu = tot * (1.f / DIM);
    const float var = totsq * (1.f / DIM) - mu * mu;
    const float rs = rsqrtf(var + LN_EPS);
    float4 gv = *(const float4*)&gamma[d];
    float4 bv = *(const float4*)&beta[d];
    v.x = (v.x - mu) * rs * gv.x + bv.x;
    v.y = (v.y - mu) * rs * gv.y + bv.y;
    v.z = (v.z - mu) * rs * gv.z + bv.z;
    v.w = (v.w - mu) * rs * gv.w + bv.w;
    *(float4*)&r[d] = v;
    if (do_split) {
        ushort4 h, l;
        h.x = f2bf(v.x); l.x = f2bf(v.x - bf2f(h.x));
        h.y = f2bf(v.y); l.y = f2bf(v.y - bf2f(h.y));
        h.z = f2bf(v.z); l.z = f2bf(v.z - bf2f(h.z));
        h.w = f2bf(v.w); l.w = f2bf(v.w - bf2f(h.w));
        *(ushort4*)&ahi[row * DIM + d] = h;
        *(ushort4*)&alo[row * DIM + d] = l;
    }
}

// ---------------------------------------------------------------------------
// Wout [K=1024][N=32000] fp32  ->  W^T hi/lo bf16 [N][K]  (transposed so the
// MFMA GEMM reads both operands k-contiguous, the verified m97 "B^T" layout)
// grid = (N/32, K/128), 256 threads
// ---------------------------------------------------------------------------
__global__ __launch_bounds__(256)
void wsplit_kernel(const float* __restrict__ W,
                   ushort* __restrict__ bhi,
                   ushort* __restrict__ blo) {
    __shared__ float tile[32][129];   // [n][k], +1 pad
    const int n0 = blockIdx.x * 32;
    const int k0 = blockIdx.y * 128;
    const int t = threadIdx.x;

    #pragma unroll
    for (int it = 0; it < 4; ++it) {
        int kk = it * 32 + (t >> 3);       // 0..127
        int nn = (t & 7) * 4;              // 0..28
        float4 v4 = *(const float4*)&W[(size_t)(k0 + kk) * VOCAB + n0 + nn];
        tile[nn + 0][kk] = v4.x;
        tile[nn + 1][kk] = v4.y;
        tile[nn + 2][kk] = v4.z;
        tile[nn + 3][kk] = v4.w;
    }
    __syncthreads();

    #pragma unroll
    for (int it = 0; it < 2; ++it) {
        int u = it * 256 + t;
        int nn = u >> 4;                   // 0..31
        int kc = (u & 15) * 8;             // 0..120
        ushortx8 h, l;
        #pragma unroll
        for (int j = 0; j < 8; ++j) {
            float f = tile[nn][kc + j];
            unsigned short hb = f2bf(f);
            h[j] = hb;
            l[j] = f2bf(f - bf2f(hb));
        }
        size_t off = (size_t)(n0 + nn) * DIM + k0 + kc;
        *(ushortx8*)&bhi[off] = h;
        *(ushortx8*)&blo[off] = l;
    }
}

// ---------------------------------------------------------------------------
// logits[M=4096, N=32000] = Ahi@BhiT + Ahi@BloT + Alo@BhiT + bias
// bf16 MFMA 16x16x32, 128x128 tile, BK=32, 4 waves (2x2), 4x4 frags/wave.
// Both operands stored [rows][K] bf16; global_load_lds width-16 staging with
// inverse-swizzled source chunks (c = slot ^ ((row>>1)&3)) so swizzled
// ds_read_b128 frag loads are bank-balanced.
// ---------------------------------------------------------------------------
__global__ __launch_bounds__(256, 2)
void logits_mfma_kernel(const ushort* __restrict__ Ahi,
                        const ushort* __restrict__ Alo,
                        const ushort* __restrict__ Bhi,
                        const ushort* __restrict__ Blo,
                        const float* __restrict__ bias,
                        float* __restrict__ C) {
    __shared__ __align__(16) ushort sAh[4096];   // [128][32] bf16, swizzled slots
    __shared__ __align__(16) ushort sAl[4096];
    __shared__ __align__(16) ushort sBh[4096];
    __shared__ __align__(16) ushort sBl[4096];

    const int tid = threadIdx.x;
    const int bid = blockIdx.x;
    // XCD-aware bijective swizzle: nwg = 8000, 8000 % 8 == 0
    const int swz = (bid & 7) * 1000 + (bid >> 3);
    const int mbase = (swz & 31) * 128;          // 32 m-tiles share one B panel
    const int nbase = (swz >> 5) * 128;          // 0..249

    // ---- staging: thread t -> row (t>>2) of half-tile, slot (t&3).
    // LDS dest is lane-linear (t*16B); source chunk is the inverse swizzle.
    const int srl = tid >> 2;                            // 0..63
    const int schunk = (tid & 3) ^ ((tid >> 3) & 3);     // k-chunk to fetch
    const size_t skofs = (size_t)schunk * 8;

    const ushort* gAh0 = Ahi + (size_t)(mbase + srl) * DIM + skofs;
    const ushort* gAh1 = Ahi + (size_t)(mbase + 64 + srl) * DIM + skofs;
    const ushort* gAl0 = Alo + (size_t)(mbase + srl) * DIM + skofs;
    const ushort* gAl1 = Alo + (size_t)(mbase + 64 + srl) * DIM + skofs;
    const ushort* gBh0 = Bhi + (size_t)(nbase + srl) * DIM + skofs;
    const ushort* gBh1 = Bhi + (size_t)(nbase + 64 + srl) * DIM + skofs;
    const ushort* gBl0 = Blo + (size_t)(nbase + srl) * DIM + skofs;
    const ushort* gBl1 = Blo + (size_t)(nbase + 64 + srl) * DIM + skofs;

    const int l0 = tid * 8;          // ushort index, instr 0 (rows 0..63)
    const int l1 = 2048 + tid * 8;   // instr 1 (rows 64..127)

    // ---- fragment read offsets (A frag: row = lane&15, k-chunk = lane>>4)
    const int lane = tid & 63;
    const int wid = tid >> 6;
    const int wr = (wid >> 1) * 64;
    const int wc = (wid & 1) * 64;
    const int lrow = lane & 15;
    const int g = lane >> 4;
    int aoff[4], boff[4];
    #pragma unroll
    for (int i = 0; i < 4; ++i) {
        int r = wr + i * 16 + lrow;
        aoff[i] = r * 32 + ((g ^ ((r >> 1) & 3)) << 3);
        int rn = wc + i * 16 + lrow;
        boff[i] = rn * 32 + ((g ^ ((rn >> 1) & 3)) << 3);
    }

    f32x4 acc[4][4];
    #pragma unroll
    for (int i = 0; i < 4; ++i)
        #pragma unroll
        for (int j = 0; j < 4; ++j)
            acc[i][j] = (f32x4){0.f, 0.f, 0.f, 0.f};

    for (int kt = 0; kt < DIM / 32; ++kt) {
        GL16(gAh0, sAh + l0);  GL16(gAh1, sAh + l1);
        GL16(gAl0, sAl + l0);  GL16(gAl1, sAl + l1);
        GL16(gBh0, sBh + l0);  GL16(gBh1, sBh + l1);
        GL16(gBl0, sBl + l0);  GL16(gBl1, sBl + l1);
        gAh0 += 32; gAh1 += 32; gAl0 += 32; gAl1 += 32;
        gBh0 += 32; gBh1 += 32; gBl0 += 32; gBl1 += 32;
        __syncthreads();                 // compiler drains vmcnt before barrier

        bf16x8 fBh[4], fBl[4];
        #pragma unroll
        for (int i = 0; i < 4; ++i) {
            fBh[i] = *(const bf16x8*)(sBh + boff[i]);
            fBl[i] = *(const bf16x8*)(sBl + boff[i]);
        }
        #pragma unroll
        for (int mi = 0; mi < 4; ++mi) {
            bf16x8 ah = *(const bf16x8*)(sAh + aoff[mi]);
            bf16x8 al = *(const bf16x8*)(sAl + aoff[mi]);
            #pragma unroll
            for (int ni = 0; ni < 4; ++ni) {
                acc[mi][ni] = __builtin_amdgcn_mfma_f32_16x16x32_bf16(ah, fBh[ni], acc[mi][ni], 0, 0, 0);
                acc[mi][ni] = __builtin_amdgcn_mfma_f32_16x16x32_bf16(ah, fBl[ni], acc[mi][ni], 0, 0, 0);
                acc[mi][ni] = __builtin_amdgcn_mfma_f32_16x16x32_bf16(al, fBh[ni], acc[mi][ni], 0, 0, 0);
            }
        }
        __syncthreads();
    }

    // C/D layout: col = lane&15, row = (lane>>4)*4 + reg   [m89-verified]
    #pragma unroll
    for (int ni = 0; ni < 4; ++ni) {
        const int c = nbase + wc + ni * 16 + lrow;
        const float bv = bias[c];
        #pragma unroll
        for (int mi = 0; mi < 4; ++mi) {
            #pragma unroll
            for (int rg = 0; rg < 4; ++rg) {
                const int r = mbase + wr + mi * 16 + g * 4 + rg;
                C[(size_t)r * VOCAB + c] = acc[mi][ni][rg] + bv;
            }
        }
    }
}

// ---------------------------------------------------------------------------
// Host launch
// ---------------------------------------------------------------------------
extern "C" void kernel_launch(void* const* d_in, const int* in_sizes, int n_in,
                              void* d_out, int out_size, void* d_ws, size_t ws_size,
                              hipStream_t stream) {
    const int*   x     = (const int*)d_in[0];
    const float* table = (const float*)d_in[1];
    const float* Wq    = (const float*)d_in[2];
    const float* bq    = (const float*)d_in[3];
    const float* Wk    = (const float*)d_in[4];
    const float* bk    = (const float*)d_in[5];
    const float* Wv    = (const float*)d_in[6];
    const float* bv    = (const float*)d_in[7];
    const float* Wo    = (const float*)d_in[8];
    const float* bo    = (const float*)d_in[9];
    const float* gamma = (const float*)d_in[10];
    const float* beta  = (const float*)d_in[11];
    const float* Wout  = (const float*)d_in[12];
    const float* bout  = (const float*)d_in[13];
    float* logits = (float*)d_out;

    const int M = BATCH * SEQ;                 // 4096
    const size_t NE = (size_t)M * DIM;         // 4 Mi floats
    const size_t SCF = (size_t)BATCH * SEQ * SEQ;

    float* ws    = (float*)d_ws;
    float* emb   = ws;
    float* q     = ws + NE;
    float* k     = ws + 2 * NE;
    float* v     = ws + 3 * NE;
    float* sc    = ws + 4 * NE;
    float* den   = sc + SCF;
    float* attn  = emb;                        // reuse
    float* out   = q;                          // reuse

    // bf16 region (16B-aligned by construction)
    ushort* ahi  = (ushort*)(den + 4096);
    ushort* alo  = ahi + NE;
    ushort* bthi = alo + NE;
    ushort* btlo = bthi + (size_t)VOCAB * DIM;
    const size_t need = (size_t)((char*)(btlo + (size_t)VOCAB * DIM) - (char*)d_ws);
    const int use_mfma = (ws_size >= need) ? 1 : 0;

    // 0. Wout transpose+split (input-only dependency; issue first)
    if (use_mfma)
        wsplit_kernel<<<dim3(VOCAB / 32, DIM / 128), 256, 0, stream>>>(Wout, bthi, btlo);

    // 1. embedding + local context
    embed_ctx_kernel<<<M, 256, 0, stream>>>(x, table, emb);

    // 2. q,k,v projections
    dim3 gq(DIM / 64, M / 64);
    gemm_kernel<1, true, false><<<gq, 256, 0, stream>>>(emb, Wq, bq, nullptr, q, M, DIM, DIM);
    gemm_kernel<1, true, false><<<gq, 256, 0, stream>>>(emb, Wk, bk, nullptr, k, M, DIM, DIM);
    gemm_kernel<0, true, false><<<gq, 256, 0, stream>>>(emb, Wv, bv, nullptr, v, M, DIM, DIM);

    // 3. causal scores + denominator
    dim3 gs(SEQ / 64, SEQ / 64, BATCH);
    scores_kernel<<<gs, 256, 0, stream>>>(q, k, sc);
    den_kernel<<<M, 256, 0, stream>>>(sc, den);

    // 4. num = scores @ v, scaled by 1/den
    dim3 gn(DIM / 64, SEQ / 64);
    for (int b = 0; b < BATCH; ++b) {
        gemm_kernel<0, false, true><<<gn, 256, 0, stream>>>(
            sc + (size_t)b * SEQ * SEQ, v + (size_t)b * SEQ * DIM,
            nullptr, den + (size_t)b * SEQ,
            attn + (size_t)b * SEQ * DIM, SEQ, DIM, SEQ);
    }

    // 5. out = attn @ Wo + bo
    gemm_kernel<0, true, false><<<gq, 256, 0, stream>>>(attn, Wo, bo, nullptr, out, M, DIM, DIM);

    // 6. LayerNorm + hi/lo bf16 split of the GEMM A-operand
    ln_split_kernel<<<M, 256, 0, stream>>>(out, gamma, beta, ahi, alo, use_mfma);

    // 7. logits = out @ Wout + bout  — bf16x3 MFMA path (fp32 fallback if ws small)
    if (use_mfma) {
        logits_mfma_kernel<<<(M / 128) * (VOCAB / 128), 256, 0, stream>>>(
            ahi, alo, bthi, btlo, bout, logits);
    } else {
        dim3 gl(VOCAB / 64, M / 64);
        gemm_kernel<0, true, false><<<gl, 256, 0, stream>>>(out, Wout, bout, nullptr, logits, M, VOCAB, DIM);
    }
}

// Round 4
// 1855.247 us; speedup vs baseline: 2.8111x; 1.3622x over previous
//
#include <hip/hip_runtime.h>
#include <cstddef>

#define DIM   1024
#define VOCAB 32000
#define BATCH 2
#define SEQ   2048
#define CTX   4
#define EPS_D 1e-6f
#define LN_EPS 1e-5f

typedef __bf16 bf16x8 __attribute__((ext_vector_type(8)));
typedef float  f32x4  __attribute__((ext_vector_type(4)));
typedef unsigned short ushortx8 __attribute__((ext_vector_type(8)));

// fp32 -> bf16 round-to-nearest-even
__device__ __forceinline__ unsigned short f2bf(float f) {
    unsigned u = __float_as_uint(f);
    u += 0x7fffu + ((u >> 16) & 1u);
    return (unsigned short)(u >> 16);
}
__device__ __forceinline__ float bf2f(unsigned short h) {
    return __uint_as_float((unsigned)h << 16);
}

// async global->LDS, 16B per lane (dest lane-linear; swizzle on GLOBAL source)
#define GL16(gp, lp) __builtin_amdgcn_global_load_lds(                        \
    (const __attribute__((address_space(1))) void*)(gp),                      \
    (__attribute__((address_space(3))) void*)(lp), 16, 0, 0)

// ---------------------------------------------------------------------------
// Embedding gather + local context sum -> hi/lo bf16 split (MFMA A operand)
// ---------------------------------------------------------------------------
__global__ __launch_bounds__(256)
void embed_split_kernel(const int* __restrict__ x,
                        const float* __restrict__ table,
                        ushort* __restrict__ eh,
                        ushort* __restrict__ el) {
    int bs = blockIdx.x;
    int b = bs >> 11;
    int s = bs & (SEQ - 1);
    int d = threadIdx.x * 4;
    float4 acc = make_float4(0.f, 0.f, 0.f, 0.f);
    #pragma unroll
    for (int o = 0; o < CTX; ++o) {
        int ss = s - o;
        if (ss >= 0) {
            int row = x[b * SEQ + ss];
            const float4 v = *(const float4*)&table[(size_t)row * DIM + d];
            acc.x += v.x; acc.y += v.y; acc.z += v.z; acc.w += v.w;
        }
    }
    ushort4 h, l;
    h.x = f2bf(acc.x); l.x = f2bf(acc.x - bf2f(h.x));
    h.y = f2bf(acc.y); l.y = f2bf(acc.y - bf2f(h.y));
    h.z = f2bf(acc.z); l.z = f2bf(acc.z - bf2f(h.z));
    h.w = f2bf(acc.w); l.w = f2bf(acc.w - bf2f(h.w));
    *(ushort4*)&eh[(size_t)bs * DIM + d] = h;
    *(ushort4*)&el[(size_t)bs * DIM + d] = l;
}

// fp32 version for fallback path
__global__ __launch_bounds__(256)
void embed_ctx_kernel(const int* __restrict__ x,
                      const float* __restrict__ table,
                      float* __restrict__ emb) {
    int bs = blockIdx.x;
    int b = bs >> 11;
    int s = bs & (SEQ - 1);
    int d = threadIdx.x * 4;
    float4 acc = make_float4(0.f, 0.f, 0.f, 0.f);
    #pragma unroll
    for (int o = 0; o < CTX; ++o) {
        int ss = s - o;
        if (ss >= 0) {
            int row = x[b * SEQ + ss];
            const float4 v = *(const float4*)&table[(size_t)row * DIM + d];
            acc.x += v.x; acc.y += v.y; acc.z += v.z; acc.w += v.w;
        }
    }
    *(float4*)&emb[(size_t)bs * DIM + d] = acc;
}

// ---------------------------------------------------------------------------
// Generic transpose + hi/lo split: W [K][N] fp32 -> th/tl [N][K] bf16
// grid = (N/32, K/128), 256 threads. K%128==0, N%32==0.
// ---------------------------------------------------------------------------
__global__ __launch_bounds__(256)
void tsplit_kernel(const float* __restrict__ W,
                   ushort* __restrict__ th,
                   ushort* __restrict__ tl,
                   int K, int N) {
    __shared__ float tile[32][129];
    const int n0 = blockIdx.x * 32;
    const int k0 = blockIdx.y * 128;
    const int t = threadIdx.x;

    #pragma unroll
    for (int it = 0; it < 4; ++it) {
        int kk = it * 32 + (t >> 3);
        int nn = (t & 7) * 4;
        float4 v4 = *(const float4*)&W[(size_t)(k0 + kk) * N + n0 + nn];
        tile[nn + 0][kk] = v4.x;
        tile[nn + 1][kk] = v4.y;
        tile[nn + 2][kk] = v4.z;
        tile[nn + 3][kk] = v4.w;
    }
    __syncthreads();

    #pragma unroll
    for (int it = 0; it < 2; ++it) {
        int u = it * 256 + t;
        int nn = u >> 4;
        int kc = (u & 15) * 8;
        ushortx8 h, l;
        #pragma unroll
        for (int j = 0; j < 8; ++j) {
            float f = tile[nn][kc + j];
            unsigned short hb = f2bf(f);
            h[j] = hb;
            l[j] = f2bf(f - bf2f(hb));
        }
        size_t off = (size_t)(n0 + nn) * K + k0 + kc;
        *(ushortx8*)&th[off] = h;
        *(ushortx8*)&tl[off] = l;
    }
}

// ---------------------------------------------------------------------------
// Generic bf16x3 MFMA GEMM: C = post( Ah@Bh^T + Ah@Bl^T + Al@Bh^T )
// Both operands stored [rows][K] bf16 hi/lo. 128x128 tile, BK=32, 4 waves.
// OM: 0 = fp32 row-major out, 1 = hi/lo split row-major, 2 = hi/lo split
//     TRANSPOSED out ([N][M] per batch slab).
// batch via blockIdx.y with element strides aBat/bBat/cBat/dBat.
// ---------------------------------------------------------------------------
template<int ACT, bool HASB, bool HASDIV, bool CAUSAL, bool TRIK, int OM>
__global__ __launch_bounds__(256, 2)
void mfma3_kernel(const ushort* __restrict__ Ah, const ushort* __restrict__ Al,
                  const ushort* __restrict__ Bh, const ushort* __restrict__ Bl,
                  const float* __restrict__ bias, const float* __restrict__ denp,
                  float* __restrict__ Cf, ushort* __restrict__ Ch, ushort* __restrict__ Cl,
                  int M, int N, int K,
                  long long aBat, long long bBat, long long cBat, long long dBat) {
    __shared__ __align__(16) ushort sAh[4096];
    __shared__ __align__(16) ushort sAl[4096];
    __shared__ __align__(16) ushort sBh[4096];
    __shared__ __align__(16) ushort sBl[4096];

    const int tid = threadIdx.x;
    const int zb = blockIdx.y;
    Ah += (size_t)zb * aBat;  Al += (size_t)zb * aBat;
    Bh += (size_t)zb * bBat;  Bl += (size_t)zb * bBat;
    if (OM == 0) { Cf += (size_t)zb * cBat; }
    else         { Ch += (size_t)zb * cBat; Cl += (size_t)zb * cBat; }
    if (HASDIV) denp += (size_t)zb * dBat;

    const int ntn = N >> 7;
    const int mbase = (blockIdx.x / ntn) << 7;
    const int nbase = (blockIdx.x % ntn) << 7;

    if (CAUSAL && nbase > mbase + 127) {     // fully masked tile -> zeros
        ushortx8 z = {0, 0, 0, 0, 0, 0, 0, 0};
        for (int u = tid * 8; u < 128 * 128; u += 2048) {
            int rr = u >> 7, cc = u & 127;
            size_t off = (size_t)(mbase + rr) * N + nbase + cc;
            *(ushortx8*)&Ch[off] = z;
            *(ushortx8*)&Cl[off] = z;
        }
        return;
    }

    // staging: thread t -> row (t>>2), LDS slot (t&3); source chunk inverse-swizzled
    const int srl = tid >> 2;
    const int schunk = (tid & 3) ^ ((tid >> 3) & 3);
    const size_t skofs = (size_t)schunk * 8;

    const ushort* gAh0 = Ah + (size_t)(mbase + srl) * K + skofs;
    const ushort* gAh1 = Ah + (size_t)(mbase + 64 + srl) * K + skofs;
    const ushort* gAl0 = Al + (size_t)(mbase + srl) * K + skofs;
    const ushort* gAl1 = Al + (size_t)(mbase + 64 + srl) * K + skofs;
    const ushort* gBh0 = Bh + (size_t)(nbase + srl) * K + skofs;
    const ushort* gBh1 = Bh + (size_t)(nbase + 64 + srl) * K + skofs;
    const ushort* gBl0 = Bl + (size_t)(nbase + srl) * K + skofs;
    const ushort* gBl1 = Bl + (size_t)(nbase + 64 + srl) * K + skofs;

    const int l0 = tid * 8;
    const int l1 = 2048 + tid * 8;

    const int lane = tid & 63;
    const int wid = tid >> 6;
    const int wr = (wid >> 1) * 64;
    const int wc = (wid & 1) * 64;
    const int lrow = lane & 15;
    const int g = lane >> 4;
    int aoff[4], boff[4];
    #pragma unroll
    for (int i = 0; i < 4; ++i) {
        int r = wr + i * 16 + lrow;
        aoff[i] = r * 32 + ((g ^ ((r >> 1) & 3)) << 3);
        int rn = wc + i * 16 + lrow;
        boff[i] = rn * 32 + ((g ^ ((rn >> 1) & 3)) << 3);
    }

    f32x4 acc[4][4];
    #pragma unroll
    for (int i = 0; i < 4; ++i)
        #pragma unroll
        for (int j = 0; j < 4; ++j)
            acc[i][j] = (f32x4){0.f, 0.f, 0.f, 0.f};

    const int ktiles = TRIK ? ((mbase + 128) >> 5) : (K >> 5);
    for (int kt = 0; kt < ktiles; ++kt) {
        GL16(gAh0, sAh + l0);  GL16(gAh1, sAh + l1);
        GL16(gAl0, sAl + l0);  GL16(gAl1, sAl + l1);
        GL16(gBh0, sBh + l0);  GL16(gBh1, sBh + l1);
        GL16(gBl0, sBl + l0);  GL16(gBl1, sBl + l1);
        gAh0 += 32; gAh1 += 32; gAl0 += 32; gAl1 += 32;
        gBh0 += 32; gBh1 += 32; gBl0 += 32; gBl1 += 32;
        __syncthreads();

        bf16x8 fBh[4], fBl[4];
        #pragma unroll
        for (int i = 0; i < 4; ++i) {
            fBh[i] = *(const bf16x8*)(sBh + boff[i]);
            fBl[i] = *(const bf16x8*)(sBl + boff[i]);
        }
        #pragma unroll
        for (int mi = 0; mi < 4; ++mi) {
            bf16x8 ah = *(const bf16x8*)(sAh + aoff[mi]);
            bf16x8 al = *(const bf16x8*)(sAl + aoff[mi]);
            #pragma unroll
            for (int ni = 0; ni < 4; ++ni) {
                acc[mi][ni] = __builtin_amdgcn_mfma_f32_16x16x32_bf16(ah, fBh[ni], acc[mi][ni], 0, 0, 0);
                acc[mi][ni] = __builtin_amdgcn_mfma_f32_16x16x32_bf16(ah, fBl[ni], acc[mi][ni], 0, 0, 0);
                acc[mi][ni] = __builtin_amdgcn_mfma_f32_16x16x32_bf16(al, fBh[ni], acc[mi][ni], 0, 0, 0);
            }
        }
        __syncthreads();
    }

    // C/D layout: col = lane&15, row = (lane>>4)*4 + reg  [m89-verified]
    #pragma unroll
    for (int ni = 0; ni < 4; ++ni) {
        const int c = nbase + wc + ni * 16 + lrow;
        float bv = 0.f;
        if (HASB) bv = bias[c];
        #pragma unroll
        for (int mi = 0; mi < 4; ++mi) {
            if (OM == 2) {
                const int r0 = mbase + wr + mi * 16 + g * 4;
                ushort4 h4, l4;
                #pragma unroll
                for (int rg = 0; rg < 4; ++rg) {
                    float vv = acc[mi][ni][rg];
                    if (HASB) vv += bv;
                    if (ACT == 1) vv = (vv > 0.f) ? (vv + 1.f) : __expf(vv);
                    unsigned short hb = f2bf(vv);
                    ((unsigned short*)&h4)[rg] = hb;
                    ((unsigned short*)&l4)[rg] = f2bf(vv - bf2f(hb));
                }
                *(ushort4*)&Ch[(size_t)c * M + r0] = h4;
                *(ushort4*)&Cl[(size_t)c * M + r0] = l4;
            } else {
                #pragma unroll
                for (int rg = 0; rg < 4; ++rg) {
                    const int r = mbase + wr + mi * 16 + g * 4 + rg;
                    float vv = acc[mi][ni][rg];
                    if (HASDIV) vv /= denp[r];
                    if (HASB) vv += bv;
                    if (ACT == 1) vv = (vv > 0.f) ? (vv + 1.f) : __expf(vv);
                    if (CAUSAL && c > r) vv = 0.f;
                    if (OM == 0) {
                        Cf[(size_t)r * N + c] = vv;
                    } else {
                        unsigned short hb = f2bf(vv);
                        Ch[(size_t)r * N + c] = hb;
                        Cl[(size_t)r * N + c] = f2bf(vv - bf2f(hb));
                    }
                }
            }
        }
    }
}

// ---------------------------------------------------------------------------
// Block reduce helper
// ---------------------------------------------------------------------------
__device__ __forceinline__ float block_reduce_sum(float v, float* red) {
    #pragma unroll
    for (int off = 32; off > 0; off >>= 1) v += __shfl_down(v, off);
    const int lane = threadIdx.x & 63;
    const int wid = threadIdx.x >> 6;
    if (lane == 0) red[wid] = v;
    __syncthreads();
    float s = red[0] + red[1] + red[2] + red[3];
    return s;
}

// den from hi/lo scores: den[b,i] = sum_j (hi+lo) + EPS
__global__ __launch_bounds__(256)
void den_bf_kernel(const ushort* __restrict__ sh,
                   const ushort* __restrict__ sl,
                   float* __restrict__ den) {
    const int row = blockIdx.x;
    const int b = row >> 11;
    const int i = row & (SEQ - 1);
    const size_t base = (size_t)b * SEQ * SEQ + (size_t)i * SEQ;
    const int j = threadIdx.x * 8;           // 256*8 == SEQ, single sweep
    ushortx8 h = *(const ushortx8*)&sh[base + j];
    ushortx8 l = *(const ushortx8*)&sl[base + j];
    float s = 0.f;
    #pragma unroll
    for (int t = 0; t < 8; ++t) s += bf2f(h[t]) + bf2f(l[t]);
    __shared__ float red[4];
    float tot = block_reduce_sum(s, red);
    if (threadIdx.x == 0) den[row] = tot + EPS_D;
}

// fp32 den for fallback
__global__ __launch_bounds__(256)
void den_kernel(const float* __restrict__ scores, float* __restrict__ den) {
    const int row = blockIdx.x;
    const int b = row >> 11;
    const int i = row & (SEQ - 1);
    const float* r = scores + (size_t)b * SEQ * SEQ + (size_t)i * SEQ;
    float s = 0.f;
    for (int j = threadIdx.x * 4; j < SEQ; j += 256 * 4) {
        float4 v = *(const float4*)&r[j];
        s += v.x + v.y + v.z + v.w;
    }
    __shared__ float red[4];
    float tot = block_reduce_sum(s, red);
    if (threadIdx.x == 0) den[row] = tot + EPS_D;
}

// ---------------------------------------------------------------------------
// LayerNorm (reads fp32) -> hi/lo bf16 split only
// ---------------------------------------------------------------------------
__global__ __launch_bounds__(256)
void ln_split_kernel(const float* __restrict__ io,
                     const float* __restrict__ gamma,
                     const float* __restrict__ beta,
                     ushort* __restrict__ ahi,
                     ushort* __restrict__ alo) {
    const size_t row = blockIdx.x;
    const float* r = io + row * DIM;
    const int d = threadIdx.x * 4;
    float4 v = *(const float4*)&r[d];
    float s = v.x + v.y + v.z + v.w;
    float sq = v.x * v.x + v.y * v.y + v.z * v.z + v.w * v.w;
    __shared__ float r1[4];
    __shared__ float r2[4];
    float tot = block_reduce_sum(s, r1);
    __syncthreads();
    float totsq = block_reduce_sum(sq, r2);
    const float mu = tot * (1.f / DIM);
    const float var = totsq * (1.f / DIM) - mu * mu;
    const float rs = rsqrtf(var + LN_EPS);
    float4 gv = *(const float4*)&gamma[d];
    float4 bv = *(const float4*)&beta[d];
    v.x = (v.x - mu) * rs * gv.x + bv.x;
    v.y = (v.y - mu) * rs * gv.y + bv.y;
    v.z = (v.z - mu) * rs * gv.z + bv.z;
    v.w = (v.w - mu) * rs * gv.w + bv.w;
    ushort4 h, l;
    h.x = f2bf(v.x); l.x = f2bf(v.x - bf2f(h.x));
    h.y = f2bf(v.y); l.y = f2bf(v.y - bf2f(h.y));
    h.z = f2bf(v.z); l.z = f2bf(v.z - bf2f(h.z));
    h.w = f2bf(v.w); l.w = f2bf(v.w - bf2f(h.w));
    *(ushort4*)&ahi[row * DIM + d] = h;
    *(ushort4*)&alo[row * DIM + d] = l;
}

// fp32 LN (fallback)
__global__ __launch_bounds__(256)
void ln_kernel(float* __restrict__ io,
               const float* __restrict__ gamma,
               const float* __restrict__ beta) {
    const size_t row = blockIdx.x;
    float* r = io + row * DIM;
    const int d = threadIdx.x * 4;
    float4 v = *(const float4*)&r[d];
    float s = v.x + v.y + v.z + v.w;
    float sq = v.x * v.x + v.y * v.y + v.z * v.z + v.w * v.w;
    __shared__ float r1[4];
    __shared__ float r2[4];
    float tot = block_reduce_sum(s, r1);
    __syncthreads();
    float totsq = block_reduce_sum(sq, r2);
    const float mu = tot * (1.f / DIM);
    const float var = totsq * (1.f / DIM) - mu * mu;
    const float rs = rsqrtf(var + LN_EPS);
    float4 gv = *(const float4*)&gamma[d];
    float4 bv = *(const float4*)&beta[d];
    v.x = (v.x - mu) * rs * gv.x + bv.x;
    v.y = (v.y - mu) * rs * gv.y + bv.y;
    v.z = (v.z - mu) * rs * gv.z + bv.z;
    v.w = (v.w - mu) * rs * gv.w + bv.w;
    *(float4*)&r[d] = v;
}

// ---------------------------------------------------------------------------
// Logits kernel — round-1 verified, + non-temporal C stores
// ---------------------------------------------------------------------------
__global__ __launch_bounds__(256, 2)
void logits_mfma_kernel(const ushort* __restrict__ Ahi,
                        const ushort* __restrict__ Alo,
                        const ushort* __restrict__ Bhi,
                        const ushort* __restrict__ Blo,
                        const float* __restrict__ bias,
                        float* __restrict__ C) {
    __shared__ __align__(16) ushort sAh[4096];
    __shared__ __align__(16) ushort sAl[4096];
    __shared__ __align__(16) ushort sBh[4096];
    __shared__ __align__(16) ushort sBl[4096];

    const int tid = threadIdx.x;
    const int bid = blockIdx.x;
    const int swz = (bid & 7) * 1000 + (bid >> 3);   // nwg = 8000, %8 == 0
    const int mbase = (swz & 31) * 128;
    const int nbase = (swz >> 5) * 128;

    const int srl = tid >> 2;
    const int schunk = (tid & 3) ^ ((tid >> 3) & 3);
    const size_t skofs = (size_t)schunk * 8;

    const ushort* gAh0 = Ahi + (size_t)(mbase + srl) * DIM + skofs;
    const ushort* gAh1 = Ahi + (size_t)(mbase + 64 + srl) * DIM + skofs;
    const ushort* gAl0 = Alo + (size_t)(mbase + srl) * DIM + skofs;
    const ushort* gAl1 = Alo + (size_t)(mbase + 64 + srl) * DIM + skofs;
    const ushort* gBh0 = Bhi + (size_t)(nbase + srl) * DIM + skofs;
    const ushort* gBh1 = Bhi + (size_t)(nbase + 64 + srl) * DIM + skofs;
    const ushort* gBl0 = Blo + (size_t)(nbase + srl) * DIM + skofs;
    const ushort* gBl1 = Blo + (size_t)(nbase + 64 + srl) * DIM + skofs;

    const int l0 = tid * 8;
    const int l1 = 2048 + tid * 8;

    const int lane = tid & 63;
    const int wid = tid >> 6;
    const int wr = (wid >> 1) * 64;
    const int wc = (wid & 1) * 64;
    const int lrow = lane & 15;
    const int g = lane >> 4;
    int aoff[4], boff[4];
    #pragma unroll
    for (int i = 0; i < 4; ++i) {
        int r = wr + i * 16 + lrow;
        aoff[i] = r * 32 + ((g ^ ((r >> 1) & 3)) << 3);
        int rn = wc + i * 16 + lrow;
        boff[i] = rn * 32 + ((g ^ ((rn >> 1) & 3)) << 3);
    }

    f32x4 acc[4][4];
    #pragma unroll
    for (int i = 0; i < 4; ++i)
        #pragma unroll
        for (int j = 0; j < 4; ++j)
            acc[i][j] = (f32x4){0.f, 0.f, 0.f, 0.f};

    for (int kt = 0; kt < DIM / 32; ++kt) {
        GL16(gAh0, sAh + l0);  GL16(gAh1, sAh + l1);
        GL16(gAl0, sAl + l0);  GL16(gAl1, sAl + l1);
        GL16(gBh0, sBh + l0);  GL16(gBh1, sBh + l1);
        GL16(gBl0, sBl + l0);  GL16(gBl1, sBl + l1);
        gAh0 += 32; gAh1 += 32; gAl0 += 32; gAl1 += 32;
        gBh0 += 32; gBh1 += 32; gBl0 += 32; gBl1 += 32;
        __syncthreads();

        bf16x8 fBh[4], fBl[4];
        #pragma unroll
        for (int i = 0; i < 4; ++i) {
            fBh[i] = *(const bf16x8*)(sBh + boff[i]);
            fBl[i] = *(const bf16x8*)(sBl + boff[i]);
        }
        #pragma unroll
        for (int mi = 0; mi < 4; ++mi) {
            bf16x8 ah = *(const bf16x8*)(sAh + aoff[mi]);
            bf16x8 al = *(const bf16x8*)(sAl + aoff[mi]);
            #pragma unroll
            for (int ni = 0; ni < 4; ++ni) {
                acc[mi][ni] = __builtin_amdgcn_mfma_f32_16x16x32_bf16(ah, fBh[ni], acc[mi][ni], 0, 0, 0);
                acc[mi][ni] = __builtin_amdgcn_mfma_f32_16x16x32_bf16(ah, fBl[ni], acc[mi][ni], 0, 0, 0);
                acc[mi][ni] = __builtin_amdgcn_mfma_f32_16x16x32_bf16(al, fBh[ni], acc[mi][ni], 0, 0, 0);
            }
        }
        __syncthreads();
    }

    #pragma unroll
    for (int ni = 0; ni < 4; ++ni) {
        const int c = nbase + wc + ni * 16 + lrow;
        const float bv = bias[c];
        #pragma unroll
        for (int mi = 0; mi < 4; ++mi) {
            #pragma unroll
            for (int rg = 0; rg < 4; ++rg) {
                const int r = mbase + wr + mi * 16 + g * 4 + rg;
                __builtin_nontemporal_store(acc[mi][ni][rg] + bv,
                                            &C[(size_t)r * VOCAB + c]);
            }
        }
    }
}

// ---------------------------------------------------------------------------
// Fallback fp32 GEMM + scores (used only if workspace too small)
// ---------------------------------------------------------------------------
template<int ACT, bool HAS_BIAS, bool HAS_DIV>
__global__ __launch_bounds__(256)
void gemm_kernel(const float* __restrict__ A,
                 const float* __restrict__ B,
                 const float* __restrict__ bias,
                 const float* __restrict__ rowdiv,
                 float* __restrict__ C,
                 int M, int N, int K) {
    __shared__ float As[16][64];
    __shared__ float Bs[16][64];

    const int tid = threadIdx.x;
    const int tx = tid & 15;
    const int ty = tid >> 4;
    const int row0 = blockIdx.y * 64;
    const int col0 = blockIdx.x * 64;

    const int a_row = tid >> 2;
    const int a_col = (tid & 3) * 4;
    const int b_row = tid >> 4;
    const int b_col = (tid & 15) * 4;

    const float* Aptr = A + (size_t)(row0 + a_row) * K + a_col;
    const float* Bptr = B + (size_t)b_row * N + col0 + b_col;

    float acc[4][4];
    #pragma unroll
    for (int i = 0; i < 4; ++i)
        #pragma unroll
        for (int j = 0; j < 4; ++j) acc[i][j] = 0.f;

    for (int k0 = 0; k0 < K; k0 += 16) {
        float4 a4 = *(const float4*)(Aptr + k0);
        float4 b4 = *(const float4*)(Bptr + (size_t)k0 * N);
        As[a_col + 0][a_row] = a4.x;
        As[a_col + 1][a_row] = a4.y;
        As[a_col + 2][a_row] = a4.z;
        As[a_col + 3][a_row] = a4.w;
        *(float4*)&Bs[b_row][b_col] = b4;
        __syncthreads();
        #pragma unroll
        for (int kk = 0; kk < 16; ++kk) {
            float4 av = *(const float4*)&As[kk][ty * 4];
            float4 bv = *(const float4*)&Bs[kk][tx * 4];
            float am[4] = {av.x, av.y, av.z, av.w};
            float bm[4] = {bv.x, bv.y, bv.z, bv.w};
            #pragma unroll
            for (int i = 0; i < 4; ++i)
                #pragma unroll
                for (int j = 0; j < 4; ++j)
                    acc[i][j] = fmaf(am[i], bm[j], acc[i][j]);
        }
        __syncthreads();
    }

    #pragma unroll
    for (int i = 0; i < 4; ++i) {
        const int r = row0 + ty * 4 + i;
        float rdiv = 1.f;
        if (HAS_DIV) rdiv = 1.f / rowdiv[r];
        #pragma unroll
        for (int j = 0; j < 4; ++j) {
            const int c = col0 + tx * 4 + j;
            float v = acc[i][j] * rdiv;
            if (HAS_BIAS) v += bias[c];
            if (ACT == 1) v = (v > 0.f) ? (v + 1.f) : __expf(v);
            C[(size_t)r * N + c] = v;
        }
    }
}

__global__ __launch_bounds__(256)
void scores_kernel(const float* __restrict__ q,
                   const float* __restrict__ k,
                   float* __restrict__ scores) {
    const int b = blockIdx.z;
    const int tid = threadIdx.x;
    const int tx = tid & 15;
    const int ty = tid >> 4;
    const int i0 = blockIdx.y * 64;
    const int j0 = blockIdx.x * 64;
    float* Sc = scores + (size_t)b * SEQ * SEQ;

    if (j0 > i0 + 63) {
        #pragma unroll
        for (int i = 0; i < 4; ++i)
            #pragma unroll
            for (int j = 0; j < 4; ++j)
                Sc[(size_t)(i0 + ty * 4 + i) * SEQ + j0 + tx * 4 + j] = 0.f;
        return;
    }

    const float* Q = q + (size_t)b * SEQ * DIM;
    const float* Kp = k + (size_t)b * SEQ * DIM;

    __shared__ float Qs[16][64];
    __shared__ float Ks[16][64];

    const int l_row = tid >> 2;
    const int l_col = (tid & 3) * 4;

    const float* Qptr = Q + (size_t)(i0 + l_row) * DIM + l_col;
    const float* Kptr = Kp + (size_t)(j0 + l_row) * DIM + l_col;

    float acc[4][4];
    #pragma unroll
    for (int i = 0; i < 4; ++i)
        #pragma unroll
        for (int j = 0; j < 4; ++j) acc[i][j] = 0.f;

    for (int d0 = 0; d0 < DIM; d0 += 16) {
        float4 a4 = *(const float4*)(Qptr + d0);
        float4 b4 = *(const float4*)(Kptr + d0);
        Qs[l_col + 0][l_row] = a4.x;
        Qs[l_col + 1][l_row] = a4.y;
        Qs[l_col + 2][l_row] = a4.z;
        Qs[l_col + 3][l_row] = a4.w;
        Ks[l_col + 0][l_row] = b4.x;
        Ks[l_col + 1][l_row] = b4.y;
        Ks[l_col + 2][l_row] = b4.z;
        Ks[l_col + 3][l_row] = b4.w;
        __syncthreads();
        #pragma unroll
        for (int kk = 0; kk < 16; ++kk) {
            float4 av = *(const float4*)&Qs[kk][ty * 4];
            float4 bv = *(const float4*)&Ks[kk][tx * 4];
            float am[4] = {av.x, av.y, av.z, av.w};
            float bm[4] = {bv.x, bv.y, bv.z, bv.w};
            #pragma unroll
            for (int i = 0; i < 4; ++i)
                #pragma unroll
                for (int j = 0; j < 4; ++j)
                    acc[i][j] = fmaf(am[i], bm[j], acc[i][j]);
        }
        __syncthreads();
    }

    #pragma unroll
    for (int i = 0; i < 4; ++i) {
        const int ii = i0 + ty * 4 + i;
        #pragma unroll
        for (int j = 0; j < 4; ++j) {
            const int jj = j0 + tx * 4 + j;
            Sc[(size_t)ii * SEQ + jj] = (jj <= ii) ? acc[i][j] : 0.f;
        }
    }
}

// ---------------------------------------------------------------------------
// Host launch
// ---------------------------------------------------------------------------
extern "C" void kernel_launch(void* const* d_in, const int* in_sizes, int n_in,
                              void* d_out, int out_size, void* d_ws, size_t ws_size,
                              hipStream_t stream) {
    const int*   x     = (const int*)d_in[0];
    const float* table = (const float*)d_in[1];
    const float* Wq    = (const float*)d_in[2];
    const float* bq    = (const float*)d_in[3];
    const float* Wk    = (const float*)d_in[4];
    const float* bk    = (const float*)d_in[5];
    const float* Wv    = (const float*)d_in[6];
    const float* bv    = (const float*)d_in[7];
    const float* Wo    = (const float*)d_in[8];
    const float* bo    = (const float*)d_in[9];
    const float* gamma = (const float*)d_in[10];
    const float* beta  = (const float*)d_in[11];
    const float* Wout  = (const float*)d_in[12];
    const float* bout  = (const float*)d_in[13];
    float* logits = (float*)d_out;

    const int M = BATCH * SEQ;                 // 4096

    // ---- workspace layout (exactly 248,528,896 B, = round-1 proven budget)
    char* p = (char*)d_ws;
    auto alloc = [&](size_t bytes) { char* r = p; p += bytes; return r; };
    ushort* WoutTh = (ushort*)alloc((size_t)VOCAB * DIM * 2);   // 65.5 MB
    ushort* WoutTl = (ushort*)alloc((size_t)VOCAB * DIM * 2);
    ushort* ehi    = (ushort*)alloc((size_t)M * DIM * 2);       // 8.39 MB
    ushort* elo    = (ushort*)alloc((size_t)M * DIM * 2);
    ushort* WqTh   = (ushort*)alloc((size_t)DIM * DIM * 2);
    ushort* WqTl   = (ushort*)alloc((size_t)DIM * DIM * 2);
    ushort* WkTh   = (ushort*)alloc((size_t)DIM * DIM * 2);
    ushort* WkTl   = (ushort*)alloc((size_t)DIM * DIM * 2);
    ushort* WvTh   = (ushort*)alloc((size_t)DIM * DIM * 2);
    ushort* WvTl   = (ushort*)alloc((size_t)DIM * DIM * 2);
    ushort* WoTh   = (ushort*)alloc((size_t)DIM * DIM * 2);
    ushort* WoTl   = (ushort*)alloc((size_t)DIM * DIM * 2);
    ushort* qhi    = (ushort*)alloc((size_t)M * DIM * 2);
    ushort* qlo    = (ushort*)alloc((size_t)M * DIM * 2);
    ushort* khi    = (ushort*)alloc((size_t)M * DIM * 2);
    ushort* klo    = (ushort*)alloc((size_t)M * DIM * 2);
    ushort* vTh    = (ushort*)alloc((size_t)BATCH * DIM * SEQ * 2);
    ushort* vTl    = (ushort*)alloc((size_t)BATCH * DIM * SEQ * 2);
    ushort* shi    = (ushort*)alloc((size_t)BATCH * SEQ * SEQ * 2); // 16.8 MB
    ushort* slo    = (ushort*)alloc((size_t)BATCH * SEQ * SEQ * 2);
    float*  den    = (float*)alloc((size_t)M * 4);
    const size_t need = (size_t)(p - (char*)d_ws);

    // aliases (liveness-checked): q dead after scores, k dead after scores,
    // e dead after v-proj
    ushort* attnh = qhi;
    ushort* attnl = qlo;
    float*  outf  = (float*)khi;               // spans khi+klo = 16.78 MB
    ushort* ahi   = ehi;
    ushort* alo   = elo;

    if (ws_size >= need) {
        // ---- MFMA pipeline ----
        // 0. weight transpose+splits
        tsplit_kernel<<<dim3(DIM / 32, DIM / 128), 256, 0, stream>>>(Wq, WqTh, WqTl, DIM, DIM);
        tsplit_kernel<<<dim3(DIM / 32, DIM / 128), 256, 0, stream>>>(Wk, WkTh, WkTl, DIM, DIM);
        tsplit_kernel<<<dim3(DIM / 32, DIM / 128), 256, 0, stream>>>(Wv, WvTh, WvTl, DIM, DIM);
        tsplit_kernel<<<dim3(DIM / 32, DIM / 128), 256, 0, stream>>>(Wo, WoTh, WoTl, DIM, DIM);
        tsplit_kernel<<<dim3(VOCAB / 32, DIM / 128), 256, 0, stream>>>(Wout, WoutTh, WoutTl, DIM, VOCAB);

        // 1. embedding + local context -> hi/lo
        embed_split_kernel<<<M, 256, 0, stream>>>(x, table, ehi, elo);

        // 2. q,k (row-major split out), v (transposed split out, per batch)
        mfma3_kernel<1, true, false, false, false, 1>
            <<<dim3((M / 128) * (DIM / 128), 1), 256, 0, stream>>>(
            ehi, elo, WqTh, WqTl, bq, nullptr, nullptr, qhi, qlo,
            M, DIM, DIM, 0, 0, 0, 0);
        mfma3_kernel<1, true, false, false, false, 1>
            <<<dim3((M / 128) * (DIM / 128), 1), 256, 0, stream>>>(
            ehi, elo, WkTh, WkTl, bk, nullptr, nullptr, khi, klo,
            M, DIM, DIM, 0, 0, 0, 0);
        mfma3_kernel<0, true, false, false, false, 2>
            <<<dim3((SEQ / 128) * (DIM / 128), BATCH), 256, 0, stream>>>(
            ehi, elo, WvTh, WvTl, bv, nullptr, nullptr, vTh, vTl,
            SEQ, DIM, DIM,
            (long long)SEQ * DIM, 0, (long long)DIM * SEQ, 0);

        // 3. causal scores (hi/lo out) + denominator
        mfma3_kernel<0, false, false, true, false, 1>
            <<<dim3((SEQ / 128) * (SEQ / 128), BATCH), 256, 0, stream>>>(
            qhi, qlo, khi, klo, nullptr, nullptr, nullptr, shi, slo,
            SEQ, SEQ, DIM,
            (long long)SEQ * DIM, (long long)SEQ * DIM, (long long)SEQ * SEQ, 0);
        den_bf_kernel<<<M, 256, 0, stream>>>(shi, slo, den);

        // 4. num = scores @ v / den  (triangular K-stop; attn hi/lo out)
        mfma3_kernel<0, false, true, false, true, 1>
            <<<dim3((SEQ / 128) * (DIM / 128), BATCH), 256, 0, stream>>>(
            shi, slo, vTh, vTl, nullptr, den, nullptr, attnh, attnl,
            SEQ, DIM, SEQ,
            (long long)SEQ * SEQ, (long long)DIM * SEQ, (long long)SEQ * DIM,
            (long long)SEQ);

        // 5. out = attn @ Wo + bo  (fp32 out for LN)
        mfma3_kernel<0, true, false, false, false, 0>
            <<<dim3((M / 128) * (DIM / 128), 1), 256, 0, stream>>>(
            attnh, attnl, WoTh, WoTl, bo, nullptr, outf, nullptr, nullptr,
            M, DIM, DIM, 0, 0, 0, 0);

        // 6. LayerNorm -> hi/lo split
        ln_split_kernel<<<M, 256, 0, stream>>>(outf, gamma, beta, ahi, alo);

        // 7. logits
        logits_mfma_kernel<<<(M / 128) * (VOCAB / 128), 256, 0, stream>>>(
            ahi, alo, WoutTh, WoutTl, bout, logits);
    } else {
        // ---- fp32 fallback pipeline (never expected; safety) ----
        const size_t NE = (size_t)M * DIM;
        float* ws    = (float*)d_ws;
        float* emb   = ws;
        float* q     = ws + NE;
        float* k     = ws + 2 * NE;
        float* v     = ws + 3 * NE;
        float* sc    = ws + 4 * NE;
        float* denf  = sc + (size_t)BATCH * SEQ * SEQ;
        float* attn  = emb;
        float* out   = q;

        embed_ctx_kernel<<<M, 256, 0, stream>>>(x, table, emb);
        dim3 gq(DIM / 64, M / 64);
        gemm_kernel<1, true, false><<<gq, 256, 0, stream>>>(emb, Wq, bq, nullptr, q, M, DIM, DIM);
        gemm_kernel<1, true, false><<<gq, 256, 0, stream>>>(emb, Wk, bk, nullptr, k, M, DIM, DIM);
        gemm_kernel<0, true, false><<<gq, 256, 0, stream>>>(emb, Wv, bv, nullptr, v, M, DIM, DIM);
        dim3 gs(SEQ / 64, SEQ / 64, BATCH);
        scores_kernel<<<gs, 256, 0, stream>>>(q, k, sc);
        den_kernel<<<M, 256, 0, stream>>>(sc, denf);
        dim3 gn(DIM / 64, SEQ / 64);
        for (int b = 0; b < BATCH; ++b) {
            gemm_kernel<0, false, true><<<gn, 256, 0, stream>>>(
                sc + (size_t)b * SEQ * SEQ, v + (size_t)b * SEQ * DIM,
                nullptr, denf + (size_t)b * SEQ,
                attn + (size_t)b * SEQ * DIM, SEQ, DIM, SEQ);
        }
        gemm_kernel<0, true, false><<<gq, 256, 0, stream>>>(attn, Wo, bo, nullptr, out, M, DIM, DIM);
        ln_kernel<<<M, 256, 0, stream>>>(out, gamma, beta);
        dim3 gl(VOCAB / 64, M / 64);
        gemm_kernel<0, true, false><<<gl, 256, 0, stream>>>(out, Wout, bout, nullptr, logits, M, VOCAB, DIM);
    }
}

// Round 5
// 1583.510 us; speedup vs baseline: 3.2935x; 1.1716x over previous
//
#include <hip/hip_runtime.h>
#include <cstddef>

#define DIM   1024
#define VOCAB 32000
#define BATCH 2
#define SEQ   2048
#define CTX   4
#define EPS_D 1e-6f
#define LN_EPS 1e-5f

typedef __bf16 bf16x8 __attribute__((ext_vector_type(8)));
typedef float  f32x4  __attribute__((ext_vector_type(4)));
typedef unsigned short ushortx8 __attribute__((ext_vector_type(8)));

// fp32 -> bf16 round-to-nearest-even
__device__ __forceinline__ unsigned short f2bf(float f) {
    unsigned u = __float_as_uint(f);
    u += 0x7fffu + ((u >> 16) & 1u);
    return (unsigned short)(u >> 16);
}
__device__ __forceinline__ float bf2f(unsigned short h) {
    return __uint_as_float((unsigned)h << 16);
}

// async global->LDS, 16B per lane (dest lane-linear; swizzle on GLOBAL source)
#define GL16(gp, lp) __builtin_amdgcn_global_load_lds(                        \
    (const __attribute__((address_space(1))) void*)(gp),                      \
    (__attribute__((address_space(3))) void*)(lp), 16, 0, 0)

// ---------------------------------------------------------------------------
// Embedding gather + local context sum -> hi/lo bf16 split (MFMA A operand)
// ---------------------------------------------------------------------------
__global__ __launch_bounds__(256)
void embed_split_kernel(const int* __restrict__ x,
                        const float* __restrict__ table,
                        ushort* __restrict__ eh,
                        ushort* __restrict__ el) {
    int bs = blockIdx.x;
    int b = bs >> 11;
    int s = bs & (SEQ - 1);
    int d = threadIdx.x * 4;
    float4 acc = make_float4(0.f, 0.f, 0.f, 0.f);
    #pragma unroll
    for (int o = 0; o < CTX; ++o) {
        int ss = s - o;
        if (ss >= 0) {
            int row = x[b * SEQ + ss];
            const float4 v = *(const float4*)&table[(size_t)row * DIM + d];
            acc.x += v.x; acc.y += v.y; acc.z += v.z; acc.w += v.w;
        }
    }
    ushort4 h, l;
    h.x = f2bf(acc.x); l.x = f2bf(acc.x - bf2f(h.x));
    h.y = f2bf(acc.y); l.y = f2bf(acc.y - bf2f(h.y));
    h.z = f2bf(acc.z); l.z = f2bf(acc.z - bf2f(h.z));
    h.w = f2bf(acc.w); l.w = f2bf(acc.w - bf2f(h.w));
    *(ushort4*)&eh[(size_t)bs * DIM + d] = h;
    *(ushort4*)&el[(size_t)bs * DIM + d] = l;
}

// fp32 version for fallback path
__global__ __launch_bounds__(256)
void embed_ctx_kernel(const int* __restrict__ x,
                      const float* __restrict__ table,
                      float* __restrict__ emb) {
    int bs = blockIdx.x;
    int b = bs >> 11;
    int s = bs & (SEQ - 1);
    int d = threadIdx.x * 4;
    float4 acc = make_float4(0.f, 0.f, 0.f, 0.f);
    #pragma unroll
    for (int o = 0; o < CTX; ++o) {
        int ss = s - o;
        if (ss >= 0) {
            int row = x[b * SEQ + ss];
            const float4 v = *(const float4*)&table[(size_t)row * DIM + d];
            acc.x += v.x; acc.y += v.y; acc.z += v.z; acc.w += v.w;
        }
    }
    *(float4*)&emb[(size_t)bs * DIM + d] = acc;
}

// ---------------------------------------------------------------------------
// Generic transpose + hi/lo split: W [K][N] fp32 -> th/tl [N][K] bf16
// grid = (N/32, K/128), 256 threads. K%128==0, N%32==0.
// ---------------------------------------------------------------------------
__device__ __forceinline__ void tsplit_body(const float* __restrict__ W,
                                            ushort* __restrict__ th,
                                            ushort* __restrict__ tl,
                                            int K, int N) {
    __shared__ float tile[32][129];
    const int n0 = blockIdx.x * 32;
    const int k0 = blockIdx.y * 128;
    const int t = threadIdx.x;

    #pragma unroll
    for (int it = 0; it < 4; ++it) {
        int kk = it * 32 + (t >> 3);
        int nn = (t & 7) * 4;
        float4 v4 = *(const float4*)&W[(size_t)(k0 + kk) * N + n0 + nn];
        tile[nn + 0][kk] = v4.x;
        tile[nn + 1][kk] = v4.y;
        tile[nn + 2][kk] = v4.z;
        tile[nn + 3][kk] = v4.w;
    }
    __syncthreads();

    #pragma unroll
    for (int it = 0; it < 2; ++it) {
        int u = it * 256 + t;
        int nn = u >> 4;
        int kc = (u & 15) * 8;
        ushortx8 h, l;
        #pragma unroll
        for (int j = 0; j < 8; ++j) {
            float f = tile[nn][kc + j];
            unsigned short hb = f2bf(f);
            h[j] = hb;
            l[j] = f2bf(f - bf2f(hb));
        }
        size_t off = (size_t)(n0 + nn) * K + k0 + kc;
        *(ushortx8*)&th[off] = h;
        *(ushortx8*)&tl[off] = l;
    }
}

__global__ __launch_bounds__(256)
void tsplit_kernel(const float* __restrict__ W,
                   ushort* __restrict__ th,
                   ushort* __restrict__ tl,
                   int K, int N) {
    tsplit_body(W, th, tl, K, N);
}

// batched version for the four DIMxDIM weights: z = {0:Wq,1:Wk,2:Wv -> qkv
// concat buffer, 3:Wo -> its own buffer}
__global__ __launch_bounds__(256)
void tsplit4_kernel(const float* __restrict__ Wq, const float* __restrict__ Wk,
                    const float* __restrict__ Wv, const float* __restrict__ Wo,
                    ushort* __restrict__ qkvTh, ushort* __restrict__ qkvTl,
                    ushort* __restrict__ WoTh,  ushort* __restrict__ WoTl) {
    const int z = blockIdx.z;
    const float* W = (z == 0) ? Wq : (z == 1) ? Wk : (z == 2) ? Wv : Wo;
    ushort* th = (z < 3) ? qkvTh + (size_t)z * DIM * DIM : WoTh;
    ushort* tl = (z < 3) ? qkvTl + (size_t)z * DIM * DIM : WoTl;
    tsplit_body(W, th, tl, DIM, DIM);
}

// ---------------------------------------------------------------------------
// Generic bf16x3 MFMA GEMM: C = post( Ah@Bh^T + Ah@Bl^T + Al@Bh^T )
// Both operands stored [rows][K] bf16 hi/lo. 128x128 tile, BK=32, 4 waves.
// OM: 0 = fp32 row-major out, 1 = hi/lo split row-major.
// CAUSAL tiles fully above the diagonal return immediately (consumers never
// read them: num uses TRIK, den masks j<=i).
// ---------------------------------------------------------------------------
template<int ACT, bool HASB, bool HASDIV, bool CAUSAL, bool TRIK, int OM>
__global__ __launch_bounds__(256, 2)
void mfma3_kernel(const ushort* __restrict__ Ah, const ushort* __restrict__ Al,
                  const ushort* __restrict__ Bh, const ushort* __restrict__ Bl,
                  const float* __restrict__ bias, const float* __restrict__ denp,
                  float* __restrict__ Cf, ushort* __restrict__ Ch, ushort* __restrict__ Cl,
                  int M, int N, int K,
                  long long aBat, long long bBat, long long cBat, long long dBat) {
    __shared__ __align__(16) ushort sAh[4096];
    __shared__ __align__(16) ushort sAl[4096];
    __shared__ __align__(16) ushort sBh[4096];
    __shared__ __align__(16) ushort sBl[4096];

    const int tid = threadIdx.x;
    const int zb = blockIdx.y;
    Ah += (size_t)zb * aBat;  Al += (size_t)zb * aBat;
    Bh += (size_t)zb * bBat;  Bl += (size_t)zb * bBat;
    if (OM == 0) { Cf += (size_t)zb * cBat; }
    else         { Ch += (size_t)zb * cBat; Cl += (size_t)zb * cBat; }
    if (HASDIV) denp += (size_t)zb * dBat;

    const int ntn = N >> 7;
    const int mbase = (blockIdx.x / ntn) << 7;
    const int nbase = (blockIdx.x % ntn) << 7;

    if (CAUSAL && nbase > mbase + 127) return;   // never consumed

    // staging: thread t -> row (t>>2), LDS slot (t&3); source chunk inverse-swizzled
    const int srl = tid >> 2;
    const int schunk = (tid & 3) ^ ((tid >> 3) & 3);
    const size_t skofs = (size_t)schunk * 8;

    const ushort* gAh0 = Ah + (size_t)(mbase + srl) * K + skofs;
    const ushort* gAh1 = Ah + (size_t)(mbase + 64 + srl) * K + skofs;
    const ushort* gAl0 = Al + (size_t)(mbase + srl) * K + skofs;
    const ushort* gAl1 = Al + (size_t)(mbase + 64 + srl) * K + skofs;
    const ushort* gBh0 = Bh + (size_t)(nbase + srl) * K + skofs;
    const ushort* gBh1 = Bh + (size_t)(nbase + 64 + srl) * K + skofs;
    const ushort* gBl0 = Bl + (size_t)(nbase + srl) * K + skofs;
    const ushort* gBl1 = Bl + (size_t)(nbase + 64 + srl) * K + skofs;

    const int l0 = tid * 8;
    const int l1 = 2048 + tid * 8;

    const int lane = tid & 63;
    const int wid = tid >> 6;
    const int wr = (wid >> 1) * 64;
    const int wc = (wid & 1) * 64;
    const int lrow = lane & 15;
    const int g = lane >> 4;
    int aoff[4], boff[4];
    #pragma unroll
    for (int i = 0; i < 4; ++i) {
        int r = wr + i * 16 + lrow;
        aoff[i] = r * 32 + ((g ^ ((r >> 1) & 3)) << 3);
        int rn = wc + i * 16 + lrow;
        boff[i] = rn * 32 + ((g ^ ((rn >> 1) & 3)) << 3);
    }

    f32x4 acc[4][4];
    #pragma unroll
    for (int i = 0; i < 4; ++i)
        #pragma unroll
        for (int j = 0; j < 4; ++j)
            acc[i][j] = (f32x4){0.f, 0.f, 0.f, 0.f};

    const int ktiles = TRIK ? ((mbase + 128) >> 5) : (K >> 5);
    for (int kt = 0; kt < ktiles; ++kt) {
        GL16(gAh0, sAh + l0);  GL16(gAh1, sAh + l1);
        GL16(gAl0, sAl + l0);  GL16(gAl1, sAl + l1);
        GL16(gBh0, sBh + l0);  GL16(gBh1, sBh + l1);
        GL16(gBl0, sBl + l0);  GL16(gBl1, sBl + l1);
        gAh0 += 32; gAh1 += 32; gAl0 += 32; gAl1 += 32;
        gBh0 += 32; gBh1 += 32; gBl0 += 32; gBl1 += 32;
        __syncthreads();

        bf16x8 fBh[4], fBl[4];
        #pragma unroll
        for (int i = 0; i < 4; ++i) {
            fBh[i] = *(const bf16x8*)(sBh + boff[i]);
            fBl[i] = *(const bf16x8*)(sBl + boff[i]);
        }
        #pragma unroll
        for (int mi = 0; mi < 4; ++mi) {
            bf16x8 ah = *(const bf16x8*)(sAh + aoff[mi]);
            bf16x8 al = *(const bf16x8*)(sAl + aoff[mi]);
            #pragma unroll
            for (int ni = 0; ni < 4; ++ni) {
                acc[mi][ni] = __builtin_amdgcn_mfma_f32_16x16x32_bf16(ah, fBh[ni], acc[mi][ni], 0, 0, 0);
                acc[mi][ni] = __builtin_amdgcn_mfma_f32_16x16x32_bf16(ah, fBl[ni], acc[mi][ni], 0, 0, 0);
                acc[mi][ni] = __builtin_amdgcn_mfma_f32_16x16x32_bf16(al, fBh[ni], acc[mi][ni], 0, 0, 0);
            }
        }
        __syncthreads();
    }

    // C/D layout: col = lane&15, row = (lane>>4)*4 + reg  [m89-verified]
    #pragma unroll
    for (int ni = 0; ni < 4; ++ni) {
        const int c = nbase + wc + ni * 16 + lrow;
        float bv = 0.f;
        if (HASB) bv = bias[c];
        #pragma unroll
        for (int mi = 0; mi < 4; ++mi) {
            #pragma unroll
            for (int rg = 0; rg < 4; ++rg) {
                const int r = mbase + wr + mi * 16 + g * 4 + rg;
                float vv = acc[mi][ni][rg];
                if (HASDIV) vv /= denp[r];
                if (HASB) vv += bv;
                if (ACT == 1) vv = (vv > 0.f) ? (vv + 1.f) : __expf(vv);
                if (CAUSAL && c > r) vv = 0.f;
                if (OM == 0) {
                    Cf[(size_t)r * N + c] = vv;
                } else {
                    unsigned short hb = f2bf(vv);
                    Ch[(size_t)r * N + c] = hb;
                    Cl[(size_t)r * N + c] = f2bf(vv - bf2f(hb));
                }
            }
        }
    }
}

// ---------------------------------------------------------------------------
// Fused QKV projection: A = emb hi/lo [4096][1024], B = Wqkv^T hi/lo
// [3072][1024]. Block-uniform mode by nbase: 0..7 -> q (elu+1), 8..15 -> k
// (elu+1), 16..23 -> v (linear, transposed out per batch slab [DIM][SEQ]).
// grid = 32 * 24 = 768 blocks.
// ---------------------------------------------------------------------------
__global__ __launch_bounds__(256, 2)
void qkvproj_kernel(const ushort* __restrict__ Ah, const ushort* __restrict__ Al,
                    const ushort* __restrict__ Bh, const ushort* __restrict__ Bl,
                    const float* __restrict__ bq, const float* __restrict__ bk,
                    const float* __restrict__ bv_,
                    ushort* __restrict__ qh, ushort* __restrict__ ql,
                    ushort* __restrict__ kh, ushort* __restrict__ kl,
                    ushort* __restrict__ vTh, ushort* __restrict__ vTl) {
    __shared__ __align__(16) ushort sAh[4096];
    __shared__ __align__(16) ushort sAl[4096];
    __shared__ __align__(16) ushort sBh[4096];
    __shared__ __align__(16) ushort sBl[4096];

    const int tid = threadIdx.x;
    const int ntn = 24;                       // 3072/128
    const int mbase = (blockIdx.x / ntn) << 7;
    const int nbase = (blockIdx.x % ntn) << 7;
    const int mode = nbase >> 10;             // 0 q, 1 k, 2 v (block-uniform)
    const int cb = nbase & 1023;

    const int srl = tid >> 2;
    const int schunk = (tid & 3) ^ ((tid >> 3) & 3);
    const size_t skofs = (size_t)schunk * 8;

    const ushort* gAh0 = Ah + (size_t)(mbase + srl) * DIM + skofs;
    const ushort* gAh1 = Ah + (size_t)(mbase + 64 + srl) * DIM + skofs;
    const ushort* gAl0 = Al + (size_t)(mbase + srl) * DIM + skofs;
    const ushort* gAl1 = Al + (size_t)(mbase + 64 + srl) * DIM + skofs;
    const ushort* gBh0 = Bh + (size_t)(nbase + srl) * DIM + skofs;
    const ushort* gBh1 = Bh + (size_t)(nbase + 64 + srl) * DIM + skofs;
    const ushort* gBl0 = Bl + (size_t)(nbase + srl) * DIM + skofs;
    const ushort* gBl1 = Bl + (size_t)(nbase + 64 + srl) * DIM + skofs;

    const int l0 = tid * 8;
    const int l1 = 2048 + tid * 8;

    const int lane = tid & 63;
    const int wid = tid >> 6;
    const int wr = (wid >> 1) * 64;
    const int wc = (wid & 1) * 64;
    const int lrow = lane & 15;
    const int g = lane >> 4;
    int aoff[4], boff[4];
    #pragma unroll
    for (int i = 0; i < 4; ++i) {
        int r = wr + i * 16 + lrow;
        aoff[i] = r * 32 + ((g ^ ((r >> 1) & 3)) << 3);
        int rn = wc + i * 16 + lrow;
        boff[i] = rn * 32 + ((g ^ ((rn >> 1) & 3)) << 3);
    }

    f32x4 acc[4][4];
    #pragma unroll
    for (int i = 0; i < 4; ++i)
        #pragma unroll
        for (int j = 0; j < 4; ++j)
            acc[i][j] = (f32x4){0.f, 0.f, 0.f, 0.f};

    for (int kt = 0; kt < DIM / 32; ++kt) {
        GL16(gAh0, sAh + l0);  GL16(gAh1, sAh + l1);
        GL16(gAl0, sAl + l0);  GL16(gAl1, sAl + l1);
        GL16(gBh0, sBh + l0);  GL16(gBh1, sBh + l1);
        GL16(gBl0, sBl + l0);  GL16(gBl1, sBl + l1);
        gAh0 += 32; gAh1 += 32; gAl0 += 32; gAl1 += 32;
        gBh0 += 32; gBh1 += 32; gBl0 += 32; gBl1 += 32;
        __syncthreads();

        bf16x8 fBh[4], fBl[4];
        #pragma unroll
        for (int i = 0; i < 4; ++i) {
            fBh[i] = *(const bf16x8*)(sBh + boff[i]);
            fBl[i] = *(const bf16x8*)(sBl + boff[i]);
        }
        #pragma unroll
        for (int mi = 0; mi < 4; ++mi) {
            bf16x8 ah = *(const bf16x8*)(sAh + aoff[mi]);
            bf16x8 al = *(const bf16x8*)(sAl + aoff[mi]);
            #pragma unroll
            for (int ni = 0; ni < 4; ++ni) {
                acc[mi][ni] = __builtin_amdgcn_mfma_f32_16x16x32_bf16(ah, fBh[ni], acc[mi][ni], 0, 0, 0);
                acc[mi][ni] = __builtin_amdgcn_mfma_f32_16x16x32_bf16(ah, fBl[ni], acc[mi][ni], 0, 0, 0);
                acc[mi][ni] = __builtin_amdgcn_mfma_f32_16x16x32_bf16(al, fBh[ni], acc[mi][ni], 0, 0, 0);
            }
        }
        __syncthreads();
    }

    const float* bias = (mode == 0) ? bq : (mode == 1) ? bk : bv_;
    ushort* dh = (mode == 0) ? qh : kh;
    ushort* dl = (mode == 0) ? ql : kl;

    #pragma unroll
    for (int ni = 0; ni < 4; ++ni) {
        const int c = cb + wc + ni * 16 + lrow;    // 0..1023 within target
        const float bvv = bias[c];
        #pragma unroll
        for (int mi = 0; mi < 4; ++mi) {
            if (mode < 2) {
                #pragma unroll
                for (int rg = 0; rg < 4; ++rg) {
                    const int r = mbase + wr + mi * 16 + g * 4 + rg;
                    float vv = acc[mi][ni][rg] + bvv;
                    vv = (vv > 0.f) ? (vv + 1.f) : __expf(vv);
                    unsigned short hb = f2bf(vv);
                    dh[(size_t)r * DIM + c] = hb;
                    dl[(size_t)r * DIM + c] = f2bf(vv - bf2f(hb));
                }
            } else {
                const int r0 = mbase + wr + mi * 16 + g * 4;
                const int batch = r0 >> 11;
                const int s0 = r0 & (SEQ - 1);
                ushort4 h4, l4;
                #pragma unroll
                for (int rg = 0; rg < 4; ++rg) {
                    float vv = acc[mi][ni][rg] + bvv;
                    unsigned short hb = f2bf(vv);
                    ((unsigned short*)&h4)[rg] = hb;
                    ((unsigned short*)&l4)[rg] = f2bf(vv - bf2f(hb));
                }
                size_t off = (size_t)batch * DIM * SEQ + (size_t)c * SEQ + s0;
                *(ushort4*)&vTh[off] = h4;
                *(ushort4*)&vTl[off] = l4;
            }
        }
    }
}

// ---------------------------------------------------------------------------
// Block reduce helper
// ---------------------------------------------------------------------------
__device__ __forceinline__ float block_reduce_sum(float v, float* red) {
    #pragma unroll
    for (int off = 32; off > 0; off >>= 1) v += __shfl_down(v, off);
    const int lane = threadIdx.x & 63;
    const int wid = threadIdx.x >> 6;
    if (lane == 0) red[wid] = v;
    __syncthreads();
    float s = red[0] + red[1] + red[2] + red[3];
    return s;
}

// den from hi/lo scores, masked to j <= i (upper triangle never written)
__global__ __launch_bounds__(256)
void den_bf_kernel(const ushort* __restrict__ sh,
                   const ushort* __restrict__ sl,
                   float* __restrict__ den) {
    const int row = blockIdx.x;
    const int b = row >> 11;
    const int i = row & (SEQ - 1);
    const size_t base = (size_t)b * SEQ * SEQ + (size_t)i * SEQ;
    const int j = threadIdx.x * 8;           // 256*8 == SEQ, single sweep
    ushortx8 h = *(const ushortx8*)&sh[base + j];
    ushortx8 l = *(const ushortx8*)&sl[base + j];
    float s = 0.f;
    int lim = i - j;                          // include t <= lim
    if (lim > 7) lim = 7;
    for (int t = 0; t <= lim; ++t) s += bf2f(h[t]) + bf2f(l[t]);
    __shared__ float red[4];
    float tot = block_reduce_sum(s, red);
    if (threadIdx.x == 0) den[row] = tot + EPS_D;
}

// fp32 den for fallback
__global__ __launch_bounds__(256)
void den_kernel(const float* __restrict__ scores, float* __restrict__ den) {
    const int row = blockIdx.x;
    const int b = row >> 11;
    const int i = row & (SEQ - 1);
    const float* r = scores + (size_t)b * SEQ * SEQ + (size_t)i * SEQ;
    float s = 0.f;
    for (int j = threadIdx.x * 4; j < SEQ; j += 256 * 4) {
        float4 v = *(const float4*)&r[j];
        s += v.x + v.y + v.z + v.w;
    }
    __shared__ float red[4];
    float tot = block_reduce_sum(s, red);
    if (threadIdx.x == 0) den[row] = tot + EPS_D;
}

// ---------------------------------------------------------------------------
// LayerNorm (reads fp32) -> hi/lo bf16 split only
// ---------------------------------------------------------------------------
__global__ __launch_bounds__(256)
void ln_split_kernel(const float* __restrict__ io,
                     const float* __restrict__ gamma,
                     const float* __restrict__ beta,
                     ushort* __restrict__ ahi,
                     ushort* __restrict__ alo) {
    const size_t row = blockIdx.x;
    const float* r = io + row * DIM;
    const int d = threadIdx.x * 4;
    float4 v = *(const float4*)&r[d];
    float s = v.x + v.y + v.z + v.w;
    float sq = v.x * v.x + v.y * v.y + v.z * v.z + v.w * v.w;
    __shared__ float r1[4];
    __shared__ float r2[4];
    float tot = block_reduce_sum(s, r1);
    __syncthreads();
    float totsq = block_reduce_sum(sq, r2);
    const float mu = tot * (1.f / DIM);
    const float var = totsq * (1.f / DIM) - mu * mu;
    const float rs = rsqrtf(var + LN_EPS);
    float4 gv = *(const float4*)&gamma[d];
    float4 bv = *(const float4*)&beta[d];
    v.x = (v.x - mu) * rs * gv.x + bv.x;
    v.y = (v.y - mu) * rs * gv.y + bv.y;
    v.z = (v.z - mu) * rs * gv.z + bv.z;
    v.w = (v.w - mu) * rs * gv.w + bv.w;
    ushort4 h, l;
    h.x = f2bf(v.x); l.x = f2bf(v.x - bf2f(h.x));
    h.y = f2bf(v.y); l.y = f2bf(v.y - bf2f(h.y));
    h.z = f2bf(v.z); l.z = f2bf(v.z - bf2f(h.z));
    h.w = f2bf(v.w); l.w = f2bf(v.w - bf2f(h.w));
    *(ushort4*)&ahi[row * DIM + d] = h;
    *(ushort4*)&alo[row * DIM + d] = l;
}

// fp32 LN (fallback)
__global__ __launch_bounds__(256)
void ln_kernel(float* __restrict__ io,
               const float* __restrict__ gamma,
               const float* __restrict__ beta) {
    const size_t row = blockIdx.x;
    float* r = io + row * DIM;
    const int d = threadIdx.x * 4;
    float4 v = *(const float4*)&r[d];
    float s = v.x + v.y + v.z + v.w;
    float sq = v.x * v.x + v.y * v.y + v.z * v.z + v.w * v.w;
    __shared__ float r1[4];
    __shared__ float r2[4];
    float tot = block_reduce_sum(s, r1);
    __syncthreads();
    float totsq = block_reduce_sum(sq, r2);
    const float mu = tot * (1.f / DIM);
    const float var = totsq * (1.f / DIM) - mu * mu;
    const float rs = rsqrtf(var + LN_EPS);
    float4 gv = *(const float4*)&gamma[d];
    float4 bv = *(const float4*)&beta[d];
    v.x = (v.x - mu) * rs * gv.x + bv.x;
    v.y = (v.y - mu) * rs * gv.y + bv.y;
    v.z = (v.z - mu) * rs * gv.z + bv.z;
    v.w = (v.w - mu) * rs * gv.w + bv.w;
    *(float4*)&r[d] = v;
}

// ---------------------------------------------------------------------------
// Logits kernel. XCD stripe swizzle: each XCD owns a 4-mbase stripe (A-stripe
// 2.1 MB stays L2-resident) and streams nbase mb-fast. Bijective:
// (xcd, idx&3, idx>>2) <-> (mb, nb); 8000 blocks, 8000 % 8 == 0.
// ---------------------------------------------------------------------------
__global__ __launch_bounds__(256, 2)
void logits_mfma_kernel(const ushort* __restrict__ Ahi,
                        const ushort* __restrict__ Alo,
                        const ushort* __restrict__ Bhi,
                        const ushort* __restrict__ Blo,
                        const float* __restrict__ bias,
                        float* __restrict__ C) {
    __shared__ __align__(16) ushort sAh[4096];
    __shared__ __align__(16) ushort sAl[4096];
    __shared__ __align__(16) ushort sBh[4096];
    __shared__ __align__(16) ushort sBl[4096];

    const int tid = threadIdx.x;
    const int bid = blockIdx.x;
    const int xcd = bid & 7;
    const int idx = bid >> 3;                 // 0..999
    const int mbase = ((xcd << 2) | (idx & 3)) * 128;  // 32 m-tiles
    const int nbase = (idx >> 2) * 128;                // 250 n-tiles

    const int srl = tid >> 2;
    const int schunk = (tid & 3) ^ ((tid >> 3) & 3);
    const size_t skofs = (size_t)schunk * 8;

    const ushort* gAh0 = Ahi + (size_t)(mbase + srl) * DIM + skofs;
    const ushort* gAh1 = Ahi + (size_t)(mbase + 64 + srl) * DIM + skofs;
    const ushort* gAl0 = Alo + (size_t)(mbase + srl) * DIM + skofs;
    const ushort* gAl1 = Alo + (size_t)(mbase + 64 + srl) * DIM + skofs;
    const ushort* gBh0 = Bhi + (size_t)(nbase + srl) * DIM + skofs;
    const ushort* gBh1 = Bhi + (size_t)(nbase + 64 + srl) * DIM + skofs;
    const ushort* gBl0 = Blo + (size_t)(nbase + srl) * DIM + skofs;
    const ushort* gBl1 = Blo + (size_t)(nbase + 64 + srl) * DIM + skofs;

    const int l0 = tid * 8;
    const int l1 = 2048 + tid * 8;

    const int lane = tid & 63;
    const int wid = tid >> 6;
    const int wr = (wid >> 1) * 64;
    const int wc = (wid & 1) * 64;
    const int lrow = lane & 15;
    const int g = lane >> 4;
    int aoff[4], boff[4];
    #pragma unroll
    for (int i = 0; i < 4; ++i) {
        int r = wr + i * 16 + lrow;
        aoff[i] = r * 32 + ((g ^ ((r >> 1) & 3)) << 3);
        int rn = wc + i * 16 + lrow;
        boff[i] = rn * 32 + ((g ^ ((rn >> 1) & 3)) << 3);
    }

    f32x4 acc[4][4];
    #pragma unroll
    for (int i = 0; i < 4; ++i)
        #pragma unroll
        for (int j = 0; j < 4; ++j)
            acc[i][j] = (f32x4){0.f, 0.f, 0.f, 0.f};

    for (int kt = 0; kt < DIM / 32; ++kt) {
        GL16(gAh0, sAh + l0);  GL16(gAh1, sAh + l1);
        GL16(gAl0, sAl + l0);  GL16(gAl1, sAl + l1);
        GL16(gBh0, sBh + l0);  GL16(gBh1, sBh + l1);
        GL16(gBl0, sBl + l0);  GL16(gBl1, sBl + l1);
        gAh0 += 32; gAh1 += 32; gAl0 += 32; gAl1 += 32;
        gBh0 += 32; gBh1 += 32; gBl0 += 32; gBl1 += 32;
        __syncthreads();

        bf16x8 fBh[4], fBl[4];
        #pragma unroll
        for (int i = 0; i < 4; ++i) {
            fBh[i] = *(const bf16x8*)(sBh + boff[i]);
            fBl[i] = *(const bf16x8*)(sBl + boff[i]);
        }
        #pragma unroll
        for (int mi = 0; mi < 4; ++mi) {
            bf16x8 ah = *(const bf16x8*)(sAh + aoff[mi]);
            bf16x8 al = *(const bf16x8*)(sAl + aoff[mi]);
            #pragma unroll
            for (int ni = 0; ni < 4; ++ni) {
                acc[mi][ni] = __builtin_amdgcn_mfma_f32_16x16x32_bf16(ah, fBh[ni], acc[mi][ni], 0, 0, 0);
                acc[mi][ni] = __builtin_amdgcn_mfma_f32_16x16x32_bf16(ah, fBl[ni], acc[mi][ni], 0, 0, 0);
                acc[mi][ni] = __builtin_amdgcn_mfma_f32_16x16x32_bf16(al, fBh[ni], acc[mi][ni], 0, 0, 0);
            }
        }
        __syncthreads();
    }

    #pragma unroll
    for (int ni = 0; ni < 4; ++ni) {
        const int c = nbase + wc + ni * 16 + lrow;
        const float bv = bias[c];
        #pragma unroll
        for (int mi = 0; mi < 4; ++mi) {
            #pragma unroll
            for (int rg = 0; rg < 4; ++rg) {
                const int r = mbase + wr + mi * 16 + g * 4 + rg;
                __builtin_nontemporal_store(acc[mi][ni][rg] + bv,
                                            &C[(size_t)r * VOCAB + c]);
            }
        }
    }
}

// ---------------------------------------------------------------------------
// Fallback fp32 GEMM + scores (used only if workspace too small)
// ---------------------------------------------------------------------------
template<int ACT, bool HAS_BIAS, bool HAS_DIV>
__global__ __launch_bounds__(256)
void gemm_kernel(const float* __restrict__ A,
                 const float* __restrict__ B,
                 const float* __restrict__ bias,
                 const float* __restrict__ rowdiv,
                 float* __restrict__ C,
                 int M, int N, int K) {
    __shared__ float As[16][64];
    __shared__ float Bs[16][64];

    const int tid = threadIdx.x;
    const int tx = tid & 15;
    const int ty = tid >> 4;
    const int row0 = blockIdx.y * 64;
    const int col0 = blockIdx.x * 64;

    const int a_row = tid >> 2;
    const int a_col = (tid & 3) * 4;
    const int b_row = tid >> 4;
    const int b_col = (tid & 15) * 4;

    const float* Aptr = A + (size_t)(row0 + a_row) * K + a_col;
    const float* Bptr = B + (size_t)b_row * N + col0 + b_col;

    float acc[4][4];
    #pragma unroll
    for (int i = 0; i < 4; ++i)
        #pragma unroll
        for (int j = 0; j < 4; ++j) acc[i][j] = 0.f;

    for (int k0 = 0; k0 < K; k0 += 16) {
        float4 a4 = *(const float4*)(Aptr + k0);
        float4 b4 = *(const float4*)(Bptr + (size_t)k0 * N);
        As[a_col + 0][a_row] = a4.x;
        As[a_col + 1][a_row] = a4.y;
        As[a_col + 2][a_row] = a4.z;
        As[a_col + 3][a_row] = a4.w;
        *(float4*)&Bs[b_row][b_col] = b4;
        __syncthreads();
        #pragma unroll
        for (int kk = 0; kk < 16; ++kk) {
            float4 av = *(const float4*)&As[kk][ty * 4];
            float4 bv = *(const float4*)&Bs[kk][tx * 4];
            float am[4] = {av.x, av.y, av.z, av.w};
            float bm[4] = {bv.x, bv.y, bv.z, bv.w};
            #pragma unroll
            for (int i = 0; i < 4; ++i)
                #pragma unroll
                for (int j = 0; j < 4; ++j)
                    acc[i][j] = fmaf(am[i], bm[j], acc[i][j]);
        }
        __syncthreads();
    }

    #pragma unroll
    for (int i = 0; i < 4; ++i) {
        const int r = row0 + ty * 4 + i;
        float rdiv = 1.f;
        if (HAS_DIV) rdiv = 1.f / rowdiv[r];
        #pragma unroll
        for (int j = 0; j < 4; ++j) {
            const int c = col0 + tx * 4 + j;
            float v = acc[i][j] * rdiv;
            if (HAS_BIAS) v += bias[c];
            if (ACT == 1) v = (v > 0.f) ? (v + 1.f) : __expf(v);
            C[(size_t)r * N + c] = v;
        }
    }
}

__global__ __launch_bounds__(256)
void scores_kernel(const float* __restrict__ q,
                   const float* __restrict__ k,
                   float* __restrict__ scores) {
    const int b = blockIdx.z;
    const int tid = threadIdx.x;
    const int tx = tid & 15;
    const int ty = tid >> 4;
    const int i0 = blockIdx.y * 64;
    const int j0 = blockIdx.x * 64;
    float* Sc = scores + (size_t)b * SEQ * SEQ;

    if (j0 > i0 + 63) {
        #pragma unroll
        for (int i = 0; i < 4; ++i)
            #pragma unroll
            for (int j = 0; j < 4; ++j)
                Sc[(size_t)(i0 + ty * 4 + i) * SEQ + j0 + tx * 4 + j] = 0.f;
        return;
    }

    const float* Q = q + (size_t)b * SEQ * DIM;
    const float* Kp = k + (size_t)b * SEQ * DIM;

    __shared__ float Qs[16][64];
    __shared__ float Ks[16][64];

    const int l_row = tid >> 2;
    const int l_col = (tid & 3) * 4;

    const float* Qptr = Q + (size_t)(i0 + l_row) * DIM + l_col;
    const float* Kptr = Kp + (size_t)(j0 + l_row) * DIM + l_col;

    float acc[4][4];
    #pragma unroll
    for (int i = 0; i < 4; ++i)
        #pragma unroll
        for (int j = 0; j < 4; ++j) acc[i][j] = 0.f;

    for (int d0 = 0; d0 < DIM; d0 += 16) {
        float4 a4 = *(const float4*)(Qptr + d0);
        float4 b4 = *(const float4*)(Kptr + d0);
        Qs[l_col + 0][l_row] = a4.x;
        Qs[l_col + 1][l_row] = a4.y;
        Qs[l_col + 2][l_row] = a4.z;
        Qs[l_col + 3][l_row] = a4.w;
        Ks[l_col + 0][l_row] = b4.x;
        Ks[l_col + 1][l_row] = b4.y;
        Ks[l_col + 2][l_row] = b4.z;
        Ks[l_col + 3][l_row] = b4.w;
        __syncthreads();
        #pragma unroll
        for (int kk = 0; kk < 16; ++kk) {
            float4 av = *(const float4*)&Qs[kk][ty * 4];
            float4 bv = *(const float4*)&Ks[kk][tx * 4];
            float am[4] = {av.x, av.y, av.z, av.w};
            float bm[4] = {bv.x, bv.y, bv.z, bv.w};
            #pragma unroll
            for (int i = 0; i < 4; ++i)
                #pragma unroll
                for (int j = 0; j < 4; ++j)
                    acc[i][j] = fmaf(am[i], bm[j], acc[i][j]);
        }
        __syncthreads();
    }

    #pragma unroll
    for (int i = 0; i < 4; ++i) {
        const int ii = i0 + ty * 4 + i;
        #pragma unroll
        for (int j = 0; j < 4; ++j) {
            const int jj = j0 + tx * 4 + j;
            Sc[(size_t)ii * SEQ + jj] = (jj <= ii) ? acc[i][j] : 0.f;
        }
    }
}

// ---------------------------------------------------------------------------
// Host launch
// ---------------------------------------------------------------------------
extern "C" void kernel_launch(void* const* d_in, const int* in_sizes, int n_in,
                              void* d_out, int out_size, void* d_ws, size_t ws_size,
                              hipStream_t stream) {
    const int*   x     = (const int*)d_in[0];
    const float* table = (const float*)d_in[1];
    const float* Wq    = (const float*)d_in[2];
    const float* bq    = (const float*)d_in[3];
    const float* Wk    = (const float*)d_in[4];
    const float* bk    = (const float*)d_in[5];
    const float* Wv    = (const float*)d_in[6];
    const float* bv    = (const float*)d_in[7];
    const float* Wo    = (const float*)d_in[8];
    const float* bo    = (const float*)d_in[9];
    const float* gamma = (const float*)d_in[10];
    const float* beta  = (const float*)d_in[11];
    const float* Wout  = (const float*)d_in[12];
    const float* bout  = (const float*)d_in[13];
    float* logits = (float*)d_out;

    const int M = BATCH * SEQ;                 // 4096

    // ---- workspace layout (exactly 248,528,896 B, round-1 proven budget)
    char* p = (char*)d_ws;
    auto alloc = [&](size_t bytes) { char* r = p; p += bytes; return r; };
    ushort* WoutTh = (ushort*)alloc((size_t)VOCAB * DIM * 2);   // 65.5 MB
    ushort* WoutTl = (ushort*)alloc((size_t)VOCAB * DIM * 2);
    ushort* ehi    = (ushort*)alloc((size_t)M * DIM * 2);       // 8.39 MB
    ushort* elo    = (ushort*)alloc((size_t)M * DIM * 2);
    ushort* WqkvTh = (ushort*)alloc((size_t)3 * DIM * DIM * 2); // concat q|k|v
    ushort* WqkvTl = (ushort*)alloc((size_t)3 * DIM * DIM * 2);
    ushort* WoTh   = (ushort*)alloc((size_t)DIM * DIM * 2);
    ushort* WoTl   = (ushort*)alloc((size_t)DIM * DIM * 2);
    ushort* qhi    = (ushort*)alloc((size_t)M * DIM * 2);
    ushort* qlo    = (ushort*)alloc((size_t)M * DIM * 2);
    ushort* khi    = (ushort*)alloc((size_t)M * DIM * 2);
    ushort* klo    = (ushort*)alloc((size_t)M * DIM * 2);
    ushort* vTh    = (ushort*)alloc((size_t)BATCH * DIM * SEQ * 2);
    ushort* vTl    = (ushort*)alloc((size_t)BATCH * DIM * SEQ * 2);
    ushort* shi    = (ushort*)alloc((size_t)BATCH * SEQ * SEQ * 2); // 16.8 MB
    ushort* slo    = (ushort*)alloc((size_t)BATCH * SEQ * SEQ * 2);
    float*  den    = (float*)alloc((size_t)M * 4);
    const size_t need = (size_t)(p - (char*)d_ws);

    // aliases (liveness-checked): q dead after scores, k dead after scores,
    // e dead after qkv-proj
    ushort* attnh = qhi;
    ushort* attnl = qlo;
    float*  outf  = (float*)khi;               // spans khi+klo = 16.78 MB
    ushort* ahi   = ehi;
    ushort* alo   = elo;

    if (ws_size >= need) {
        // ---- MFMA pipeline ----
        // 0. weight transpose+splits (one batched launch + Wout)
        tsplit4_kernel<<<dim3(DIM / 32, DIM / 128, 4), 256, 0, stream>>>(
            Wq, Wk, Wv, Wo, WqkvTh, WqkvTl, WoTh, WoTl);
        tsplit_kernel<<<dim3(VOCAB / 32, DIM / 128), 256, 0, stream>>>(
            Wout, WoutTh, WoutTl, DIM, VOCAB);

        // 1. embedding + local context -> hi/lo
        embed_split_kernel<<<M, 256, 0, stream>>>(x, table, ehi, elo);

        // 2. fused q,k,v projection (one launch, 768 blocks)
        qkvproj_kernel<<<(M / 128) * 24, 256, 0, stream>>>(
            ehi, elo, WqkvTh, WqkvTl, bq, bk, bv,
            qhi, qlo, khi, klo, vTh, vTl);

        // 3. causal scores (hi/lo out; masked tiles skipped) + denominator
        mfma3_kernel<0, false, false, true, false, 1>
            <<<dim3((SEQ / 128) * (SEQ / 128), BATCH), 256, 0, stream>>>(
            qhi, qlo, khi, klo, nullptr, nullptr, nullptr, shi, slo,
            SEQ, SEQ, DIM,
            (long long)SEQ * DIM, (long long)SEQ * DIM, (long long)SEQ * SEQ, 0);
        den_bf_kernel<<<M, 256, 0, stream>>>(shi, slo, den);

        // 4. num = scores @ v / den  (triangular K-stop; attn hi/lo out)
        mfma3_kernel<0, false, true, false, true, 1>
            <<<dim3((SEQ / 128) * (DIM / 128), BATCH), 256, 0, stream>>>(
            shi, slo, vTh, vTl, nullptr, den, nullptr, attnh, attnl,
            SEQ, DIM, SEQ,
            (long long)SEQ * SEQ, (long long)DIM * SEQ, (long long)SEQ * DIM,
            (long long)SEQ);

        // 5. out = attn @ Wo + bo  (fp32 out for LN)
        mfma3_kernel<0, true, false, false, false, 0>
            <<<dim3((M / 128) * (DIM / 128), 1), 256, 0, stream>>>(
            attnh, attnl, WoTh, WoTl, bo, nullptr, outf, nullptr, nullptr,
            M, DIM, DIM, 0, 0, 0, 0);

        // 6. LayerNorm -> hi/lo split
        ln_split_kernel<<<M, 256, 0, stream>>>(outf, gamma, beta, ahi, alo);

        // 7. logits (XCD stripe swizzle)
        logits_mfma_kernel<<<(M / 128) * (VOCAB / 128), 256, 0, stream>>>(
            ahi, alo, WoutTh, WoutTl, bout, logits);
    } else {
        // ---- fp32 fallback pipeline (never expected; safety) ----
        const size_t NE = (size_t)M * DIM;
        float* ws    = (float*)d_ws;
        float* emb   = ws;
        float* q     = ws + NE;
        float* k     = ws + 2 * NE;
        float* v     = ws + 3 * NE;
        float* sc    = ws + 4 * NE;
        float* denf  = sc + (size_t)BATCH * SEQ * SEQ;
        float* attn  = emb;
        float* out   = q;

        embed_ctx_kernel<<<M, 256, 0, stream>>>(x, table, emb);
        dim3 gq(DIM / 64, M / 64);
        gemm_kernel<1, true, false><<<gq, 256, 0, stream>>>(emb, Wq, bq, nullptr, q, M, DIM, DIM);
        gemm_kernel<1, true, false><<<gq, 256, 0, stream>>>(emb, Wk, bk, nullptr, k, M, DIM, DIM);
        gemm_kernel<0, true, false><<<gq, 256, 0, stream>>>(emb, Wv, bv, nullptr, v, M, DIM, DIM);
        dim3 gs(SEQ / 64, SEQ / 64, BATCH);
        scores_kernel<<<gs, 256, 0, stream>>>(q, k, sc);
        den_kernel<<<M, 256, 0, stream>>>(sc, denf);
        dim3 gn(DIM / 64, SEQ / 64);
        for (int b = 0; b < BATCH; ++b) {
            gemm_kernel<0, false, true><<<gn, 256, 0, stream>>>(
                sc + (size_t)b * SEQ * SEQ, v + (size_t)b * SEQ * DIM,
                nullptr, denf + (size_t)b * SEQ,
                attn + (size_t)b * SEQ * DIM, SEQ, DIM, SEQ);
        }
        gemm_kernel<0, true, false><<<gq, 256, 0, stream>>>(attn, Wo, bo, nullptr, out, M, DIM, DIM);
        ln_kernel<<<M, 256, 0, stream>>>(out, gamma, beta);
        dim3 gl(VOCAB / 64, M / 64);
        gemm_kernel<0, true, false><<<gl, 256, 0, stream>>>(out, Wout, bout, nullptr, logits, M, VOCAB, DIM);
    }
}